// Round 3
// baseline (223.101 us; speedup 1.0000x reference)
//
#include <hip/hip_runtime.h>
#include <hip/hip_bf16.h>
#include <stdint.h>

#define NB 4096
#define NCOL 100
#define NCOND 64
#define NTOTAL 6400
#define NRODT 1600
#define NEST 160
#define NFOR 100
#define NHID 128
#define NCLS 10
#define GEPS 1e-5f

typedef __attribute__((ext_vector_type(8))) short short8;
typedef __attribute__((ext_vector_type(4))) float floatx4;

// round-half-up f32->bf16: 2 VALU ops; tie-only difference vs RNE
__device__ __forceinline__ unsigned f2bfu(float x) {
  union { float f; unsigned u; } v; v.f = x;
  return (v.u + 0x8000u) >> 16;
}
__device__ __forceinline__ float bf2f(unsigned short u) {
  union { unsigned u; float f; } v; v.u = ((unsigned)u) << 16;
  return v.f;
}

// all-reduce sum over the 16-lane DPP row -- VALU pipe, no LDS.
__device__ __forceinline__ float rowsum16(float v) {
  union { float f; int i; } a, t;
  a.f = v;
  t.i = __builtin_amdgcn_update_dpp(0, a.i, 0x128, 0xf, 0xf, true); a.f += t.f; // ror:8
  t.i = __builtin_amdgcn_update_dpp(0, a.i, 0x124, 0xf, 0xf, true); a.f += t.f; // ror:4
  t.i = __builtin_amdgcn_update_dpp(0, a.i, 0x122, 0xf, 0xf, true); a.f += t.f; // ror:2
  t.i = __builtin_amdgcn_update_dpp(0, a.i, 0x121, 0xf, 0xf, true); a.f += t.f; // ror:1
  return a.f;
}

// ---------------------------------------------------------------------------
// K01: merged prep kernel (single launch). Unchanged from R19.
//  blocks [0,1600)    : k1 -- ConditionGeneration+perm+phi_2 -> exp(w)^T bf16
//  blocks [1600,1702) : k0 -- fragment-pack Bf / W1f / W2f (identity k-map)
//  blocks [1702,1705) : zero d_out
// ---------------------------------------------------------------------------
__global__ __launch_bounds__(256) void k01_prep(
    const float* __restrict__ x, const float* __restrict__ w1,
    const float* __restrict__ b1, const int* __restrict__ perm,
    const float* __restrict__ gn1w, const float* __restrict__ gn1b,
    const float* __restrict__ c2w, const float* __restrict__ c2b,
    const float* __restrict__ gn2w, const float* __restrict__ gn2b,
    const float* __restrict__ c3w, const float* __restrict__ c3b,
    const float* __restrict__ E, const int* __restrict__ swr,
    const float* __restrict__ fc1w, const float* __restrict__ fc2w,
    unsigned short* __restrict__ wT,
    unsigned short* __restrict__ Bf, unsigned short* __restrict__ W1f,
    unsigned short* __restrict__ W2f, float* __restrict__ out)
{
  __shared__ float xl[64 * NCOL];          // k1 path only (25.6 KB)
  __shared__ int ridx[NEST];               // k0 path only
  const int tid = threadIdx.x;
  const int blk = blockIdx.x;

  if (blk < 1600) {
    // ---------------- k1: phi_2 logits -> exp -> bf16, transposed ----------
    const int b0 = (blk & 63) * 64;
    const int g  = (blk >> 6) * 64 + (tid >> 2);
    const int i4 = tid & 3;
    for (int i = tid; i < 64 * NCOL; i += 256)
      xl[i] = x[(size_t)b0 * NCOL + i];
    __syncthreads();

    const int4 p4 = *(const int4*)(perm + 4 * g);
    const int pv[4] = {p4.x, p4.y, p4.z, p4.w};
    float w1v[4], b1v[4];
    int pc[4];
#pragma unroll
    for (int i = 0; i < 4; i++) {
      unsigned p = (unsigned)pv[i];
      unsigned j = p / 100u;
      unsigned cc = p - j * 100u;
      pc[i] = (int)cc;
      w1v[i] = w1[cc * NCOND + j];
      b1v[i] = b1[cc * NCOND + j];
    }
    const float4 g1w = *(const float4*)(gn1w + 4 * g);
    const float4 g1b = *(const float4*)(gn1b + 4 * g);
    const float4 cw0 = *(const float4*)(c2w + 16 * g);
    const float4 cw1 = *(const float4*)(c2w + 16 * g + 4);
    const float4 cw2 = *(const float4*)(c2w + 16 * g + 8);
    const float4 cw3 = *(const float4*)(c2w + 16 * g + 12);
    const float4 cbv = *(const float4*)(c2b + 4 * g);
    const float4 g2w = *(const float4*)(gn2w + 4 * g);
    const float4 g2b = *(const float4*)(gn2b + 4 * g);
    const float4 c3v = *(const float4*)(c3w + 4 * g);
    const float c3bv = c3b[g];

    for (int k = 0; k < 4; k++) {
      float v4[4];
#pragma unroll
      for (int j = 0; j < 4; j++) {
        const int bb = k * 16 + i4 * 4 + j;
        float O[4];
#pragma unroll
        for (int i = 0; i < 4; i++) {
          float a = xl[bb * NCOL + pc[i]] * w1v[i] + b1v[i];
          O[i] = 1.0f / (1.0f + __expf(-a));
        }
        float mu = 0.25f * (O[0] + O[1] + O[2] + O[3]);
        float d[4], var = 0.f;
#pragma unroll
        for (int i = 0; i < 4; i++) { d[i] = O[i] - mu; var += d[i] * d[i]; }
        float rs = rsqrtf(0.25f * var + GEPS);
        float xn0 = d[0] * rs * g1w.x + g1b.x;
        float xn1 = d[1] * rs * g1w.y + g1b.y;
        float xn2 = d[2] * rs * g1w.z + g1b.z;
        float xn3 = d[3] * rs * g1w.w + g1b.w;
        float h[4];
        h[0] = xn0*cw0.x + xn1*cw1.x + xn2*cw2.x + xn3*cw3.x + cbv.x;
        h[1] = xn0*cw0.y + xn1*cw1.y + xn2*cw2.y + xn3*cw3.y + cbv.y;
        h[2] = xn0*cw0.z + xn1*cw1.z + xn2*cw2.z + xn3*cw3.z + cbv.z;
        h[3] = xn0*cw0.w + xn1*cw1.w + xn2*cw2.w + xn3*cw3.w + cbv.w;
#pragma unroll
        for (int i = 0; i < 4; i++) h[i] = fmaxf(h[i], 0.f);
        float mu2 = 0.25f * (h[0] + h[1] + h[2] + h[3]);
        float e[4], var2 = 0.f;
#pragma unroll
        for (int i = 0; i < 4; i++) { e[i] = h[i] - mu2; var2 += e[i] * e[i]; }
        float rs2 = rsqrtf(0.25f * var2 + GEPS);
        float hn0 = e[0] * rs2 * g2w.x + g2b.x;
        float hn1 = e[1] * rs2 * g2w.y + g2b.y;
        float hn2 = e[2] * rs2 * g2w.z + g2b.z;
        float hn3 = e[3] * rs2 * g2w.w + g2b.w;
        v4[j] = hn0*c3v.x + hn1*c3v.y + hn2*c3v.z + hn3*c3v.w + c3bv;
      }
      // store exp(logit): k3's softmax numerator, once per unique (g,b)
      uint2 pk;
      pk.x = f2bfu(__expf(v4[0])) | (f2bfu(__expf(v4[1])) << 16);
      pk.y = f2bfu(__expf(v4[2])) | (f2bfu(__expf(v4[3])) << 16);
      *(uint2*)(wT + (size_t)g * NB + b0 + k * 16 + i4 * 4) = pk;
    }
  } else if (blk < 1600 + NFOR) {
    // ---------------- k0: Bf fragment pack ----------------
    const int fblk = blk - 1600;
    if (tid < NEST) ridx[tid] = swr[fblk * NEST + tid];
    __syncthreads();
    for (int m = tid; m < 2560; m += 256) {        // m = (n*5+kc)*64 + lane
      int lane = m & 63, rest = m >> 6;
      int kc = rest % 5, n = rest / 5;
      int q = lane >> 4, c = lane & 15;
      int e0 = kc * 32 + q * 8;
      int h = n * 16 + c;
      union { unsigned short v[8]; uint4 u; } t;
#pragma unroll
      for (int j = 0; j < 8; j++)
        t.v[j] = (unsigned short)f2bfu(E[(size_t)ridx[e0 + j] * NHID + h]);
      *(uint4*)(Bf + (size_t)fblk * 20480 + (size_t)m * 8) = t.u;
    }
  } else if (blk == 1600 + NFOR) {
    // ---------------- k0: W1f (identity k-map) ----------------
    for (int m = tid; m < 2048; m += 256) {        // m = (n*4+kc)*64 + lane
      int lane = m & 63, rest = m >> 6;
      int kc = rest & 3, n = rest >> 2;
      int q = lane >> 4, c = lane & 15;
      int k0 = kc * 32 + q * 8;
      int o = n * 16 + c;
      union { unsigned short v[8]; uint4 u; } t;
#pragma unroll
      for (int j = 0; j < 8; j++)
        t.v[j] = (unsigned short)f2bfu(fc1w[(size_t)(k0 + j) * NHID + o]);
      *(uint4*)(W1f + (size_t)m * 8) = t.u;
    }
  } else if (blk == 1601 + NFOR) {
    // ---------------- k0: W2f (identity k-map) ----------------
    for (int m = tid; m < 256; m += 256) {         // m = kc*64 + lane
      int lane = m & 63, kc = m >> 6;
      int q = lane >> 4, c = lane & 15;
      int k0 = kc * 32 + q * 8;
      union { unsigned short v[8]; uint4 u; } t;
#pragma unroll
      for (int j = 0; j < 8; j++)
        t.v[j] = (unsigned short)f2bfu(c < NCLS ? fc2w[(size_t)(k0 + j) * NCLS + c] : 0.f);
      *(uint4*)(W2f + (size_t)m * 8) = t.u;
    }
  } else {
    // ---------------- zero d_out (3 blocks) ----------------
    const int z = blk - (1602 + NFOR);
    float4 zz = make_float4(0.f, 0.f, 0.f, 0.f);
    for (int i = z * 256 + tid; i < NB * NCLS / 4; i += 3 * 256)
      ((float4*)out)[i] = zz;
  }
}

// ---------------------------------------------------------------------------
// K3 (R20): single-forest straight-line pipeline with deep-MLP gather.
//  R19 post-mortem: VGPR=40 (launch_bounds(256,6) + compiler minimization)
//  left the gather with only ~8 loads in flight x 5 serial batches; ~47% of
//  cycles were memory waits. This round:
//   - __launch_bounds__(256,4): VGPR cap 128, trade a little TLP for MLP
//   - gather in TWO 20-deep load batches (was five 8-deep)
//   - GEMM1 kc=0 B-fragments prefetched BEFORE the barrier (Bf independent
//     of gather); GEMM2 n=0 W1f fragments issued under LN1
//  Straight-line body, statically-indexed register arrays only (R18 lesson:
//  no loop-carried accumulator state -> no scratch spills).
// ---------------------------------------------------------------------------
__global__ __launch_bounds__(256, 4) void k3_mfma(
    const unsigned short* __restrict__ wT,    // [1600][B] bf16 exp(logits)^T
    const int* __restrict__ swr,
    const unsigned short* __restrict__ Bf,    // [f][8][5][64][8]
    const unsigned short* __restrict__ W1f,   // [8][4][64][8]
    const unsigned short* __restrict__ W2f,   // [4][64][8]
    const float* __restrict__ ln1w, const float* __restrict__ ln1b,
    const float* __restrict__ fc1b,
    const float* __restrict__ ln2w, const float* __restrict__ ln2b,
    const float* __restrict__ fc2b,
    float* __restrict__ out)
{
  __shared__ unsigned short lsA[64 * 168];    // 21504 B
  __shared__ __align__(16) float sPT[64][4];  // per-row wave partials (transposed)

  const int tid = threadIdx.x;
  const int b0 = blockIdx.x * 64;
  const int f  = blockIdx.y;
  const int lane = tid & 63;
  const int wv = __builtin_amdgcn_readfirstlane(tid >> 6);  // wave-uniform SGPR
  const int c = lane & 15, q = lane >> 4;

  const unsigned short* bbase = Bf + (size_t)f * 20480 + lane * 8;

  // ---- gather phase: wave wv covers e in [40wv, 40wv+40); 2x20-deep ----
  {
    const unsigned short* wbase = wT + b0 + lane;
    const int* swf = swr + f * NEST + wv * 40;   // wave-uniform -> s_load
    float ssum = 0.f;
    unsigned short us[40];
#pragma unroll
    for (int h = 0; h < 2; h++) {
      int idx[20];
#pragma unroll
      for (int e = 0; e < 20; e++) idx[e] = swf[h * 20 + e];
#pragma unroll
      for (int e = 0; e < 20; e++)
        us[h * 20 + e] = wbase[(size_t)idx[e] * NB];   // 20 loads in flight
#pragma unroll
      for (int e = 0; e < 20; e++) ssum += bf2f(us[h * 20 + e]);
    }
#pragma unroll
    for (int k = 0; k < 5; k++) {
      uint4 pk = {(unsigned)us[k*8+0] | ((unsigned)us[k*8+1] << 16),
                  (unsigned)us[k*8+2] | ((unsigned)us[k*8+3] << 16),
                  (unsigned)us[k*8+4] | ((unsigned)us[k*8+5] << 16),
                  (unsigned)us[k*8+6] | ((unsigned)us[k*8+7] << 16)};
      *(uint4*)(lsA + lane * 168 + wv * 40 + k * 8) = pk;
    }
    sPT[lane][wv] = ssum;
  }

  // ---- prefetch GEMM1 kc=0 B-fragments (independent of gather/barrier) ----
  short8 bp[8];
#pragma unroll
  for (int n = 0; n < 8; n++)
    bp[n] = *(const short8*)(bbase + n * 2560);

  __syncthreads();                     // the ONLY barrier

  // ---- GEMM1: (exp-ws)[64x160] @ Ep[160x128]  (kc-outer) ----
  const unsigned short* pa = lsA + (wv * 16 + c) * 168 + q * 8;
  floatx4 acc[8];
  {
    short8 a0 = *(const short8*)(pa);
#pragma unroll
    for (int n = 0; n < 8; n++)
      acc[n] = __builtin_amdgcn_mfma_f32_16x16x32_bf16(
          a0, bp[n], (floatx4){0.f, 0.f, 0.f, 0.f}, 0, 0, 0);
  }
#pragma unroll
  for (int kc = 1; kc < 5; kc++) {
    short8 a = *(const short8*)(pa + kc * 32);
#pragma unroll
    for (int n = 0; n < 8; n++) {
      short8 b = *(const short8*)(bbase + n * 2560 + kc * 512);
      acc[n] = __builtin_amdgcn_mfma_f32_16x16x32_bf16(a, b, acc[n], 0, 0, 0);
    }
  }

  // ---- issue GEMM2 n=0 W1f fragments now; latency hides under LN1 ----
  const unsigned short* w1p = W1f + lane * 8;
  short8 w10 = *(const short8*)(w1p);
  short8 w11 = *(const short8*)(w1p + 512);
  short8 w12 = *(const short8*)(w1p + 1024);
  short8 w13 = *(const short8*)(w1p + 1536);

  // ---- LN1 with softmax fold: LN(x/s) == (x-mu)*rsqrt(var + eps*s^2) ----
  {
    float lw[8], lb[8];
#pragma unroll
    for (int n = 0; n < 8; n++) { lw[n] = ln1w[n * 16 + c]; lb[n] = ln1b[n * 16 + c]; }
#pragma unroll
    for (int rr = 0; rr < 4; rr++) {
      const int row = wv * 16 + q * 4 + rr;
      const float4 sv = *(const float4*)&sPT[row][0];   // one ds_read_b128
      float st = sv.x + sv.y + sv.z + sv.w;
      float s1 = 0.f, s2 = 0.f;
#pragma unroll
      for (int n = 0; n < 8; n++) { float v = acc[n][rr]; s1 += v; s2 += v * v; }
      s1 = rowsum16(s1);
      s2 = rowsum16(s2);
      float mu = s1 * (1.f / 128.f);
      float var = fmaxf(s2 * (1.f / 128.f) - mu * mu, 0.f);
      float rs = rsqrtf(var + GEPS * st * st);
#pragma unroll
      for (int n = 0; n < 8; n++)
        acc[n][rr] = (acc[n][rr] - mu) * rs * lw[n] + lb[n];
    }
  }

  // ---- Fn -> lsA (A-layout bf16, wave-private rows; no barrier needed) ----
#pragma unroll
  for (int rr = 0; rr < 4; rr++)
#pragma unroll
    for (int n = 0; n < 8; n++)
      lsA[(wv * 16 + q * 4 + rr) * 168 + n * 16 + c] =
          (unsigned short)f2bfu(acc[n][rr]);

  // ---- GEMM2: H = Fn[64x128] @ fc1w[128x128]  (kc-outer) ----
  {
    short8 a0 = *(const short8*)(pa);
    short8 a1 = *(const short8*)(pa + 32);
    short8 a2 = *(const short8*)(pa + 64);
    short8 a3 = *(const short8*)(pa + 96);
    acc[0] = __builtin_amdgcn_mfma_f32_16x16x32_bf16(a0, w10, (floatx4){0.f,0.f,0.f,0.f}, 0, 0, 0);
    acc[0] = __builtin_amdgcn_mfma_f32_16x16x32_bf16(a1, w11, acc[0], 0, 0, 0);
    acc[0] = __builtin_amdgcn_mfma_f32_16x16x32_bf16(a2, w12, acc[0], 0, 0, 0);
    acc[0] = __builtin_amdgcn_mfma_f32_16x16x32_bf16(a3, w13, acc[0], 0, 0, 0);
#pragma unroll
    for (int n = 1; n < 8; n++) {
      const unsigned short* wp = w1p + n * 2048;
      acc[n] = __builtin_amdgcn_mfma_f32_16x16x32_bf16(a0, *(const short8*)(wp),        (floatx4){0.f,0.f,0.f,0.f}, 0, 0, 0);
      acc[n] = __builtin_amdgcn_mfma_f32_16x16x32_bf16(a1, *(const short8*)(wp + 512),  acc[n], 0, 0, 0);
      acc[n] = __builtin_amdgcn_mfma_f32_16x16x32_bf16(a2, *(const short8*)(wp + 1024), acc[n], 0, 0, 0);
      acc[n] = __builtin_amdgcn_mfma_f32_16x16x32_bf16(a3, *(const short8*)(wp + 1536), acc[n], 0, 0, 0);
    }
  }

  // ---- bias + ReLU + LN2 (DPP row-reduce) ----
  {
    float fb[8], lw[8], lb[8];
#pragma unroll
    for (int n = 0; n < 8; n++) {
      fb[n] = fc1b[n * 16 + c];
      lw[n] = ln2w[n * 16 + c]; lb[n] = ln2b[n * 16 + c];
    }
#pragma unroll
    for (int rr = 0; rr < 4; rr++) {
#pragma unroll
      for (int n = 0; n < 8; n++) acc[n][rr] = fmaxf(acc[n][rr] + fb[n], 0.f);
      float s1 = 0.f, s2 = 0.f;
#pragma unroll
      for (int n = 0; n < 8; n++) { float v = acc[n][rr]; s1 += v; s2 += v * v; }
      s1 = rowsum16(s1);
      s2 = rowsum16(s2);
      float mu = s1 * (1.f / 128.f);
      float var = fmaxf(s2 * (1.f / 128.f) - mu * mu, 0.f);
      float rs = rsqrtf(var + GEPS);
#pragma unroll
      for (int n = 0; n < 8; n++)
        acc[n][rr] = (acc[n][rr] - mu) * rs * lw[n] + lb[n];
    }
  }

  // ---- H2 -> lsA (A-layout, wave-private rows; no barrier) ----
#pragma unroll
  for (int rr = 0; rr < 4; rr++)
#pragma unroll
    for (int n = 0; n < 8; n++)
      lsA[(wv * 16 + q * 4 + rr) * 168 + n * 16 + c] =
          (unsigned short)f2bfu(acc[n][rr]);

  // ---- fc2 (16-col padded tile) + mean-atomic ----
  floatx4 o4 = (floatx4){0.f, 0.f, 0.f, 0.f};
#pragma unroll
  for (int kc = 0; kc < 4; kc++) {
    short8 a = *(const short8*)(pa + kc * 32);
    short8 b = *(const short8*)(W2f + kc * 512 + lane * 8);
    o4 = __builtin_amdgcn_mfma_f32_16x16x32_bf16(a, b, o4, 0, 0, 0);
  }
  if (c < NCLS) {
    float bias = fc2b[c];
#pragma unroll
    for (int rr = 0; rr < 4; rr++)
      atomicAdd(out + (size_t)(b0 + wv * 16 + q * 4 + rr) * NCLS + c,
                (o4[rr] + bias) * 0.01f);
  }
}

// ---------------------------------------------------------------------------
extern "C" void kernel_launch(void* const* d_in, const int* in_sizes, int n_in,
                              void* d_out, int out_size, void* d_ws, size_t ws_size,
                              hipStream_t stream)
{
  (void)in_sizes; (void)n_in; (void)ws_size; (void)out_size;
  const float* x    = (const float*)d_in[0];
  const float* w1   = (const float*)d_in[1];
  const float* b1   = (const float*)d_in[2];
  const int*   perm = (const int*)d_in[3];
  const float* gn1w = (const float*)d_in[4];
  const float* gn1b = (const float*)d_in[5];
  const float* c2w  = (const float*)d_in[6];
  const float* c2b  = (const float*)d_in[7];
  const float* gn2w = (const float*)d_in[8];
  const float* gn2b = (const float*)d_in[9];
  const float* c3w  = (const float*)d_in[10];
  const float* c3b  = (const float*)d_in[11];
  const int*   swr  = (const int*)d_in[12];
  const float* E    = (const float*)d_in[13];
  const float* ln1w = (const float*)d_in[14];
  const float* ln1b = (const float*)d_in[15];
  const float* fc1w = (const float*)d_in[16];
  const float* fc1b = (const float*)d_in[17];
  const float* ln2w = (const float*)d_in[18];
  const float* ln2b = (const float*)d_in[19];
  const float* fc2w = (const float*)d_in[20];
  const float* fc2b = (const float*)d_in[21];
  float* out = (float*)d_out;

  // workspace layout:
  //   [0, 13.1MB)       : wT exp-logits bf16 [1600][B]
  //   [13.1MB, +4.10MB) : Bf (100*20480 shorts)
  //   then W1f 32,768 B, W2f 4,096 B
  const size_t W_BYTES = (size_t)NB * NRODT * 2;     // 13,107,200
  unsigned short* wTbuf = (unsigned short*)d_ws;
  unsigned short* Bfb   = (unsigned short*)((char*)d_ws + W_BYTES);
  unsigned short* W1fb  = (unsigned short*)((char*)d_ws + W_BYTES + 4096000);
  unsigned short* W2fb  = (unsigned short*)((char*)d_ws + W_BYTES + 4096000 + 32768);

  k01_prep<<<1600 + NFOR + 2 + 3, 256, 0, stream>>>(
      x, w1, b1, perm, gn1w, gn1b, c2w, c2b, gn2w, gn2b, c3w, c3b,
      E, swr, fc1w, fc2w, wTbuf, Bfb, W1fb, W2fb, out);
  dim3 g3(NB / 64, NFOR);
  k3_mfma<<<g3, 256, 0, stream>>>(wTbuf, swr, Bfb, W1fb, W2fb,
                                  ln1w, ln1b, fc1b, ln2w, ln2b, fc2b, out);
}

// Round 4
// 211.132 us; speedup vs baseline: 1.0567x; 1.0567x over previous
//
#include <hip/hip_runtime.h>
#include <hip/hip_bf16.h>
#include <stdint.h>

#define NB 4096
#define NCOL 100
#define NCOND 64
#define NTOTAL 6400
#define NRODT 1600
#define NEST 160
#define NFOR 100
#define NHID 128
#define NCLS 10
#define GEPS 1e-5f

typedef __attribute__((ext_vector_type(8))) short short8;
typedef __attribute__((ext_vector_type(4))) float floatx4;

// round-half-up f32->bf16: 2 VALU ops; tie-only difference vs RNE
__device__ __forceinline__ unsigned f2bfu(float x) {
  union { float f; unsigned u; } v; v.f = x;
  return (v.u + 0x8000u) >> 16;
}
__device__ __forceinline__ float bf2f(unsigned short u) {
  union { unsigned u; float f; } v; v.u = ((unsigned)u) << 16;
  return v.f;
}

// all-reduce sum over the 16-lane DPP row -- VALU pipe, no LDS.
__device__ __forceinline__ float rowsum16(float v) {
  union { float f; int i; } a, t;
  a.f = v;
  t.i = __builtin_amdgcn_update_dpp(0, a.i, 0x128, 0xf, 0xf, true); a.f += t.f; // ror:8
  t.i = __builtin_amdgcn_update_dpp(0, a.i, 0x124, 0xf, 0xf, true); a.f += t.f; // ror:4
  t.i = __builtin_amdgcn_update_dpp(0, a.i, 0x122, 0xf, 0xf, true); a.f += t.f; // ror:2
  t.i = __builtin_amdgcn_update_dpp(0, a.i, 0x121, 0xf, 0xf, true); a.f += t.f; // ror:1
  return a.f;
}

// ---------------------------------------------------------------------------
// K01: merged prep kernel (single launch). Unchanged (proven).
//  blocks [0,1600)    : k1 -- ConditionGeneration+perm+phi_2 -> exp(w)^T bf16
//  blocks [1600,1702) : k0 -- fragment-pack Bf / W1f / W2f (identity k-map)
//  blocks [1702,1705) : zero d_out
// ---------------------------------------------------------------------------
__global__ __launch_bounds__(256) void k01_prep(
    const float* __restrict__ x, const float* __restrict__ w1,
    const float* __restrict__ b1, const int* __restrict__ perm,
    const float* __restrict__ gn1w, const float* __restrict__ gn1b,
    const float* __restrict__ c2w, const float* __restrict__ c2b,
    const float* __restrict__ gn2w, const float* __restrict__ gn2b,
    const float* __restrict__ c3w, const float* __restrict__ c3b,
    const float* __restrict__ E, const int* __restrict__ swr,
    const float* __restrict__ fc1w, const float* __restrict__ fc2w,
    unsigned short* __restrict__ wT,
    unsigned short* __restrict__ Bf, unsigned short* __restrict__ W1f,
    unsigned short* __restrict__ W2f, float* __restrict__ out)
{
  __shared__ float xl[64 * NCOL];          // k1 path only (25.6 KB)
  __shared__ int ridx[NEST];               // k0 path only
  const int tid = threadIdx.x;
  const int blk = blockIdx.x;

  if (blk < 1600) {
    // ---------------- k1: phi_2 logits -> exp -> bf16, transposed ----------
    const int b0 = (blk & 63) * 64;
    const int g  = (blk >> 6) * 64 + (tid >> 2);
    const int i4 = tid & 3;
    for (int i = tid; i < 64 * NCOL; i += 256)
      xl[i] = x[(size_t)b0 * NCOL + i];
    __syncthreads();

    const int4 p4 = *(const int4*)(perm + 4 * g);
    const int pv[4] = {p4.x, p4.y, p4.z, p4.w};
    float w1v[4], b1v[4];
    int pc[4];
#pragma unroll
    for (int i = 0; i < 4; i++) {
      unsigned p = (unsigned)pv[i];
      unsigned j = p / 100u;
      unsigned cc = p - j * 100u;
      pc[i] = (int)cc;
      w1v[i] = w1[cc * NCOND + j];
      b1v[i] = b1[cc * NCOND + j];
    }
    const float4 g1w = *(const float4*)(gn1w + 4 * g);
    const float4 g1b = *(const float4*)(gn1b + 4 * g);
    const float4 cw0 = *(const float4*)(c2w + 16 * g);
    const float4 cw1 = *(const float4*)(c2w + 16 * g + 4);
    const float4 cw2 = *(const float4*)(c2w + 16 * g + 8);
    const float4 cw3 = *(const float4*)(c2w + 16 * g + 12);
    const float4 cbv = *(const float4*)(c2b + 4 * g);
    const float4 g2w = *(const float4*)(gn2w + 4 * g);
    const float4 g2b = *(const float4*)(gn2b + 4 * g);
    const float4 c3v = *(const float4*)(c3w + 4 * g);
    const float c3bv = c3b[g];

    for (int k = 0; k < 4; k++) {
      float v4[4];
#pragma unroll
      for (int j = 0; j < 4; j++) {
        const int bb = k * 16 + i4 * 4 + j;
        float O[4];
#pragma unroll
        for (int i = 0; i < 4; i++) {
          float a = xl[bb * NCOL + pc[i]] * w1v[i] + b1v[i];
          O[i] = 1.0f / (1.0f + __expf(-a));
        }
        float mu = 0.25f * (O[0] + O[1] + O[2] + O[3]);
        float d[4], var = 0.f;
#pragma unroll
        for (int i = 0; i < 4; i++) { d[i] = O[i] - mu; var += d[i] * d[i]; }
        float rs = rsqrtf(0.25f * var + GEPS);
        float xn0 = d[0] * rs * g1w.x + g1b.x;
        float xn1 = d[1] * rs * g1w.y + g1b.y;
        float xn2 = d[2] * rs * g1w.z + g1b.z;
        float xn3 = d[3] * rs * g1w.w + g1b.w;
        float h[4];
        h[0] = xn0*cw0.x + xn1*cw1.x + xn2*cw2.x + xn3*cw3.x + cbv.x;
        h[1] = xn0*cw0.y + xn1*cw1.y + xn2*cw2.y + xn3*cw3.y + cbv.y;
        h[2] = xn0*cw0.z + xn1*cw1.z + xn2*cw2.z + xn3*cw3.z + cbv.z;
        h[3] = xn0*cw0.w + xn1*cw1.w + xn2*cw2.w + xn3*cw3.w + cbv.w;
#pragma unroll
        for (int i = 0; i < 4; i++) h[i] = fmaxf(h[i], 0.f);
        float mu2 = 0.25f * (h[0] + h[1] + h[2] + h[3]);
        float e[4], var2 = 0.f;
#pragma unroll
        for (int i = 0; i < 4; i++) { e[i] = h[i] - mu2; var2 += e[i] * e[i]; }
        float rs2 = rsqrtf(0.25f * var2 + GEPS);
        float hn0 = e[0] * rs2 * g2w.x + g2b.x;
        float hn1 = e[1] * rs2 * g2w.y + g2b.y;
        float hn2 = e[2] * rs2 * g2w.z + g2b.z;
        float hn3 = e[3] * rs2 * g2w.w + g2b.w;
        v4[j] = hn0*c3v.x + hn1*c3v.y + hn2*c3v.z + hn3*c3v.w + c3bv;
      }
      // store exp(logit): k3's softmax numerator, once per unique (g,b)
      uint2 pk;
      pk.x = f2bfu(__expf(v4[0])) | (f2bfu(__expf(v4[1])) << 16);
      pk.y = f2bfu(__expf(v4[2])) | (f2bfu(__expf(v4[3])) << 16);
      *(uint2*)(wT + (size_t)g * NB + b0 + k * 16 + i4 * 4) = pk;
    }
  } else if (blk < 1600 + NFOR) {
    // ---------------- k0: Bf fragment pack ----------------
    const int fblk = blk - 1600;
    if (tid < NEST) ridx[tid] = swr[fblk * NEST + tid];
    __syncthreads();
    for (int m = tid; m < 2560; m += 256) {        // m = (n*5+kc)*64 + lane
      int lane = m & 63, rest = m >> 6;
      int kc = rest % 5, n = rest / 5;
      int q = lane >> 4, c = lane & 15;
      int e0 = kc * 32 + q * 8;
      int h = n * 16 + c;
      union { unsigned short v[8]; uint4 u; } t;
#pragma unroll
      for (int j = 0; j < 8; j++)
        t.v[j] = (unsigned short)f2bfu(E[(size_t)ridx[e0 + j] * NHID + h]);
      *(uint4*)(Bf + (size_t)fblk * 20480 + (size_t)m * 8) = t.u;
    }
  } else if (blk == 1600 + NFOR) {
    // ---------------- k0: W1f (identity k-map) ----------------
    for (int m = tid; m < 2048; m += 256) {        // m = (n*4+kc)*64 + lane
      int lane = m & 63, rest = m >> 6;
      int kc = rest & 3, n = rest >> 2;
      int q = lane >> 4, c = lane & 15;
      int k0 = kc * 32 + q * 8;
      int o = n * 16 + c;
      union { unsigned short v[8]; uint4 u; } t;
#pragma unroll
      for (int j = 0; j < 8; j++)
        t.v[j] = (unsigned short)f2bfu(fc1w[(size_t)(k0 + j) * NHID + o]);
      *(uint4*)(W1f + (size_t)m * 8) = t.u;
    }
  } else if (blk == 1601 + NFOR) {
    // ---------------- k0: W2f (identity k-map) ----------------
    for (int m = tid; m < 256; m += 256) {         // m = kc*64 + lane
      int lane = m & 63, kc = m >> 6;
      int q = lane >> 4, c = lane & 15;
      int k0 = kc * 32 + q * 8;
      union { unsigned short v[8]; uint4 u; } t;
#pragma unroll
      for (int j = 0; j < 8; j++)
        t.v[j] = (unsigned short)f2bfu(c < NCLS ? fc2w[(size_t)(k0 + j) * NCLS + c] : 0.f);
      *(uint4*)(W2f + (size_t)m * 8) = t.u;
    }
  } else {
    // ---------------- zero d_out (3 blocks) ----------------
    const int z = blk - (1602 + NFOR);
    float4 zz = make_float4(0.f, 0.f, 0.f, 0.f);
    for (int i = z * 256 + tid; i < NB * NCLS / 4; i += 3 * 256)
      ((float4*)out)[i] = zz;
  }
}

// ---------------------------------------------------------------------------
// K3 (R21): M=128 per block -- two b-tiles sharing every B-fragment load.
//  R20 post-mortem: deeper per-wave MLP did NOT help -> stall is VMEM-pipe
//  contention, not per-wave latency. Bf/W1f loads are wave-invariant (4x
//  redundant) and row-amortized: doubling rows per block halves B-operand
//  VMEM traffic per row (~36% fewer VMEM instrs per CU).
//  Structure is R19's proven straight-line body, duplicated for tile0/tile1
//  with STATICALLY-indexed register arrays only (R18 lesson: no spills).
//  LDS 45 KB -> 3 blocks/CU (close to the ~4.4 achieved before).
// ---------------------------------------------------------------------------
__global__ __launch_bounds__(256, 3) void k3_mfma(
    const unsigned short* __restrict__ wT,    // [1600][B] bf16 exp(logits)^T
    const int* __restrict__ swr,
    const unsigned short* __restrict__ Bf,    // [f][8][5][64][8]
    const unsigned short* __restrict__ W1f,   // [8][4][64][8]
    const unsigned short* __restrict__ W2f,   // [4][64][8]
    const float* __restrict__ ln1w, const float* __restrict__ ln1b,
    const float* __restrict__ fc1b,
    const float* __restrict__ ln2w, const float* __restrict__ ln2b,
    const float* __restrict__ fc2b,
    float* __restrict__ out)
{
  __shared__ unsigned short lsA[128 * 168];   // 43008 B (rows 0-63 t0, 64-127 t1)
  __shared__ __align__(16) float sPT[128][4]; // per-row wave partials (transposed)

  const int tid = threadIdx.x;
  const int b0 = blockIdx.x * 128;
  const int f  = blockIdx.y;
  const int lane = tid & 63;
  const int wv = __builtin_amdgcn_readfirstlane(tid >> 6);  // wave-uniform SGPR
  const int c = lane & 15, q = lane >> 4;

  // ---- gather phase: wave wv covers e in [40wv,40wv+40) for BOTH tiles ----
  // tile1 column is +64: same voffset, +128B immediate -> ~free addressing.
  {
    const unsigned short* wbase = wT + b0 + lane;
    const int* swf = swr + f * NEST + wv * 40;   // wave-uniform -> s_load
    float ssum0 = 0.f, ssum1 = 0.f;
#pragma unroll
    for (int k = 0; k < 5; k++) {
      int id8[8];
#pragma unroll
      for (int jj = 0; jj < 8; jj++) id8[jj] = swf[k * 8 + jj];
      unsigned short us0[8], us1[8];
#pragma unroll
      for (int jj = 0; jj < 8; jj++) {
        const unsigned short* p = wbase + (size_t)id8[jj] * NB;
        us0[jj] = p[0];
        us1[jj] = p[64];
        ssum0 += bf2f(us0[jj]);
        ssum1 += bf2f(us1[jj]);
      }
      uint4 pk0 = {(unsigned)us0[0] | ((unsigned)us0[1] << 16),
                   (unsigned)us0[2] | ((unsigned)us0[3] << 16),
                   (unsigned)us0[4] | ((unsigned)us0[5] << 16),
                   (unsigned)us0[6] | ((unsigned)us0[7] << 16)};
      uint4 pk1 = {(unsigned)us1[0] | ((unsigned)us1[1] << 16),
                   (unsigned)us1[2] | ((unsigned)us1[3] << 16),
                   (unsigned)us1[4] | ((unsigned)us1[5] << 16),
                   (unsigned)us1[6] | ((unsigned)us1[7] << 16)};
      *(uint4*)(lsA + lane * 168 + wv * 40 + k * 8) = pk0;
      *(uint4*)(lsA + (64 + lane) * 168 + wv * 40 + k * 8) = pk1;
    }
    sPT[lane][wv] = ssum0;
    sPT[64 + lane][wv] = ssum1;
  }
  __syncthreads();                     // the ONLY barrier

  // ---- GEMM1: (exp-ws)[128x160] @ Ep[160x128]; B loaded once per 2 tiles --
  const unsigned short* pa0 = lsA + (wv * 16 + c) * 168 + q * 8;
  const unsigned short* pa1 = pa0 + 64 * 168;
  floatx4 acc0[8], acc1[8];
#pragma unroll
  for (int n = 0; n < 8; n++) {
    acc0[n] = (floatx4){0.f, 0.f, 0.f, 0.f};
    acc1[n] = (floatx4){0.f, 0.f, 0.f, 0.f};
  }
  const unsigned short* bbase = Bf + (size_t)f * 20480 + lane * 8;
#pragma unroll
  for (int kc = 0; kc < 5; kc++) {
    short8 a0 = *(const short8*)(pa0 + kc * 32);
    short8 a1 = *(const short8*)(pa1 + kc * 32);
#pragma unroll
    for (int n = 0; n < 8; n++) {
      short8 b = *(const short8*)(bbase + n * 2560 + kc * 512);
      acc0[n] = __builtin_amdgcn_mfma_f32_16x16x32_bf16(a0, b, acc0[n], 0, 0, 0);
      acc1[n] = __builtin_amdgcn_mfma_f32_16x16x32_bf16(a1, b, acc1[n], 0, 0, 0);
    }
  }

  // ---- LN1 (both tiles): LN(x/s) == (x-mu)*rsqrt(var + eps*s^2) ----
  {
    float lw[8], lb[8];
#pragma unroll
    for (int n = 0; n < 8; n++) { lw[n] = ln1w[n * 16 + c]; lb[n] = ln1b[n * 16 + c]; }
#pragma unroll
    for (int rr = 0; rr < 4; rr++) {
      const int row = wv * 16 + q * 4 + rr;
      {
        const float4 sv = *(const float4*)&sPT[row][0];
        float st = sv.x + sv.y + sv.z + sv.w;
        float s1 = 0.f, s2 = 0.f;
#pragma unroll
        for (int n = 0; n < 8; n++) { float v = acc0[n][rr]; s1 += v; s2 += v * v; }
        s1 = rowsum16(s1);
        s2 = rowsum16(s2);
        float mu = s1 * (1.f / 128.f);
        float var = fmaxf(s2 * (1.f / 128.f) - mu * mu, 0.f);
        float rs = rsqrtf(var + GEPS * st * st);
#pragma unroll
        for (int n = 0; n < 8; n++)
          acc0[n][rr] = (acc0[n][rr] - mu) * rs * lw[n] + lb[n];
      }
      {
        const float4 sv = *(const float4*)&sPT[64 + row][0];
        float st = sv.x + sv.y + sv.z + sv.w;
        float s1 = 0.f, s2 = 0.f;
#pragma unroll
        for (int n = 0; n < 8; n++) { float v = acc1[n][rr]; s1 += v; s2 += v * v; }
        s1 = rowsum16(s1);
        s2 = rowsum16(s2);
        float mu = s1 * (1.f / 128.f);
        float var = fmaxf(s2 * (1.f / 128.f) - mu * mu, 0.f);
        float rs = rsqrtf(var + GEPS * st * st);
#pragma unroll
        for (int n = 0; n < 8; n++)
          acc1[n][rr] = (acc1[n][rr] - mu) * rs * lw[n] + lb[n];
      }
    }
  }

  // ---- Fn -> lsA (A-layout bf16, wave-private rows; no barrier needed) ----
#pragma unroll
  for (int rr = 0; rr < 4; rr++)
#pragma unroll
    for (int n = 0; n < 8; n++) {
      lsA[(wv * 16 + q * 4 + rr) * 168 + n * 16 + c] =
          (unsigned short)f2bfu(acc0[n][rr]);
      lsA[(64 + wv * 16 + q * 4 + rr) * 168 + n * 16 + c] =
          (unsigned short)f2bfu(acc1[n][rr]);
    }

  // ---- GEMM2: H = Fn[128x128] @ fc1w[128x128]; W1f loaded once per 2 tiles -
  {
    short8 a00 = *(const short8*)(pa0);
    short8 a01 = *(const short8*)(pa0 + 32);
    short8 a02 = *(const short8*)(pa0 + 64);
    short8 a03 = *(const short8*)(pa0 + 96);
    short8 a10 = *(const short8*)(pa1);
    short8 a11 = *(const short8*)(pa1 + 32);
    short8 a12 = *(const short8*)(pa1 + 64);
    short8 a13 = *(const short8*)(pa1 + 96);
    const unsigned short* w1p = W1f + lane * 8;
#pragma unroll
    for (int n = 0; n < 8; n++) {
      const unsigned short* wp = w1p + n * 2048;
      short8 b0v = *(const short8*)(wp);
      short8 b1v = *(const short8*)(wp + 512);
      short8 b2v = *(const short8*)(wp + 1024);
      short8 b3v = *(const short8*)(wp + 1536);
      floatx4 t0 = __builtin_amdgcn_mfma_f32_16x16x32_bf16(a00, b0v, (floatx4){0.f,0.f,0.f,0.f}, 0, 0, 0);
      t0 = __builtin_amdgcn_mfma_f32_16x16x32_bf16(a01, b1v, t0, 0, 0, 0);
      t0 = __builtin_amdgcn_mfma_f32_16x16x32_bf16(a02, b2v, t0, 0, 0, 0);
      t0 = __builtin_amdgcn_mfma_f32_16x16x32_bf16(a03, b3v, t0, 0, 0, 0);
      floatx4 t1 = __builtin_amdgcn_mfma_f32_16x16x32_bf16(a10, b0v, (floatx4){0.f,0.f,0.f,0.f}, 0, 0, 0);
      t1 = __builtin_amdgcn_mfma_f32_16x16x32_bf16(a11, b1v, t1, 0, 0, 0);
      t1 = __builtin_amdgcn_mfma_f32_16x16x32_bf16(a12, b2v, t1, 0, 0, 0);
      t1 = __builtin_amdgcn_mfma_f32_16x16x32_bf16(a13, b3v, t1, 0, 0, 0);
      acc0[n] = t0;
      acc1[n] = t1;
    }
  }

  // ---- bias + ReLU + LN2 (both tiles, DPP row-reduce) ----
  {
    float fb[8], lw[8], lb[8];
#pragma unroll
    for (int n = 0; n < 8; n++) {
      fb[n] = fc1b[n * 16 + c];
      lw[n] = ln2w[n * 16 + c]; lb[n] = ln2b[n * 16 + c];
    }
#pragma unroll
    for (int rr = 0; rr < 4; rr++) {
      {
#pragma unroll
        for (int n = 0; n < 8; n++) acc0[n][rr] = fmaxf(acc0[n][rr] + fb[n], 0.f);
        float s1 = 0.f, s2 = 0.f;
#pragma unroll
        for (int n = 0; n < 8; n++) { float v = acc0[n][rr]; s1 += v; s2 += v * v; }
        s1 = rowsum16(s1);
        s2 = rowsum16(s2);
        float mu = s1 * (1.f / 128.f);
        float var = fmaxf(s2 * (1.f / 128.f) - mu * mu, 0.f);
        float rs = rsqrtf(var + GEPS);
#pragma unroll
        for (int n = 0; n < 8; n++)
          acc0[n][rr] = (acc0[n][rr] - mu) * rs * lw[n] + lb[n];
      }
      {
#pragma unroll
        for (int n = 0; n < 8; n++) acc1[n][rr] = fmaxf(acc1[n][rr] + fb[n], 0.f);
        float s1 = 0.f, s2 = 0.f;
#pragma unroll
        for (int n = 0; n < 8; n++) { float v = acc1[n][rr]; s1 += v; s2 += v * v; }
        s1 = rowsum16(s1);
        s2 = rowsum16(s2);
        float mu = s1 * (1.f / 128.f);
        float var = fmaxf(s2 * (1.f / 128.f) - mu * mu, 0.f);
        float rs = rsqrtf(var + GEPS);
#pragma unroll
        for (int n = 0; n < 8; n++)
          acc1[n][rr] = (acc1[n][rr] - mu) * rs * lw[n] + lb[n];
      }
    }
  }

  // ---- H2 -> lsA (A-layout, wave-private rows; no barrier) ----
#pragma unroll
  for (int rr = 0; rr < 4; rr++)
#pragma unroll
    for (int n = 0; n < 8; n++) {
      lsA[(wv * 16 + q * 4 + rr) * 168 + n * 16 + c] =
          (unsigned short)f2bfu(acc0[n][rr]);
      lsA[(64 + wv * 16 + q * 4 + rr) * 168 + n * 16 + c] =
          (unsigned short)f2bfu(acc1[n][rr]);
    }

  // ---- fc2 (16-col padded tile), W2f loaded once per 2 tiles ----
  floatx4 o40 = (floatx4){0.f, 0.f, 0.f, 0.f};
  floatx4 o41 = (floatx4){0.f, 0.f, 0.f, 0.f};
#pragma unroll
  for (int kc = 0; kc < 4; kc++) {
    short8 a0 = *(const short8*)(pa0 + kc * 32);
    short8 a1 = *(const short8*)(pa1 + kc * 32);
    short8 b = *(const short8*)(W2f + kc * 512 + lane * 8);
    o40 = __builtin_amdgcn_mfma_f32_16x16x32_bf16(a0, b, o40, 0, 0, 0);
    o41 = __builtin_amdgcn_mfma_f32_16x16x32_bf16(a1, b, o41, 0, 0, 0);
  }
  if (c < NCLS) {
    float bias = fc2b[c];
#pragma unroll
    for (int rr = 0; rr < 4; rr++) {
      atomicAdd(out + (size_t)(b0 + wv * 16 + q * 4 + rr) * NCLS + c,
                (o40[rr] + bias) * 0.01f);
      atomicAdd(out + (size_t)(b0 + 64 + wv * 16 + q * 4 + rr) * NCLS + c,
                (o41[rr] + bias) * 0.01f);
    }
  }
}

// ---------------------------------------------------------------------------
extern "C" void kernel_launch(void* const* d_in, const int* in_sizes, int n_in,
                              void* d_out, int out_size, void* d_ws, size_t ws_size,
                              hipStream_t stream)
{
  (void)in_sizes; (void)n_in; (void)ws_size; (void)out_size;
  const float* x    = (const float*)d_in[0];
  const float* w1   = (const float*)d_in[1];
  const float* b1   = (const float*)d_in[2];
  const int*   perm = (const int*)d_in[3];
  const float* gn1w = (const float*)d_in[4];
  const float* gn1b = (const float*)d_in[5];
  const float* c2w  = (const float*)d_in[6];
  const float* c2b  = (const float*)d_in[7];
  const float* gn2w = (const float*)d_in[8];
  const float* gn2b = (const float*)d_in[9];
  const float* c3w  = (const float*)d_in[10];
  const float* c3b  = (const float*)d_in[11];
  const int*   swr  = (const int*)d_in[12];
  const float* E    = (const float*)d_in[13];
  const float* ln1w = (const float*)d_in[14];
  const float* ln1b = (const float*)d_in[15];
  const float* fc1w = (const float*)d_in[16];
  const float* fc1b = (const float*)d_in[17];
  const float* ln2w = (const float*)d_in[18];
  const float* ln2b = (const float*)d_in[19];
  const float* fc2w = (const float*)d_in[20];
  const float* fc2b = (const float*)d_in[21];
  float* out = (float*)d_out;

  // workspace layout:
  //   [0, 13.1MB)       : wT exp-logits bf16 [1600][B]
  //   [13.1MB, +4.10MB) : Bf (100*20480 shorts)
  //   then W1f 32,768 B, W2f 4,096 B
  const size_t W_BYTES = (size_t)NB * NRODT * 2;     // 13,107,200
  unsigned short* wTbuf = (unsigned short*)d_ws;
  unsigned short* Bfb   = (unsigned short*)((char*)d_ws + W_BYTES);
  unsigned short* W1fb  = (unsigned short*)((char*)d_ws + W_BYTES + 4096000);
  unsigned short* W2fb  = (unsigned short*)((char*)d_ws + W_BYTES + 4096000 + 32768);

  k01_prep<<<1600 + NFOR + 2 + 3, 256, 0, stream>>>(
      x, w1, b1, perm, gn1w, gn1b, c2w, c2b, gn2w, gn2b, c3w, c3b,
      E, swr, fc1w, fc2w, wTbuf, Bfb, W1fb, W2fb, out);
  dim3 g3(NB / 128, NFOR);
  k3_mfma<<<g3, 256, 0, stream>>>(wTbuf, swr, Bfb, W1fb, W2fb,
                                  ln1w, ln1b, fc1b, ln2w, ln2b, fc2b, out);
}

// Round 5
// 209.276 us; speedup vs baseline: 1.0661x; 1.0089x over previous
//
#include <hip/hip_runtime.h>
#include <hip/hip_bf16.h>
#include <stdint.h>

#define NB 4096
#define NCOL 100
#define NCOND 64
#define NTOTAL 6400
#define NRODT 1600
#define NEST 160
#define NFOR 100
#define NHID 128
#define NCLS 10
#define GEPS 1e-5f

typedef __attribute__((ext_vector_type(8))) short short8;
typedef __attribute__((ext_vector_type(4))) float floatx4;

// round-half-up f32->bf16: 2 VALU ops; tie-only difference vs RNE
__device__ __forceinline__ unsigned f2bfu(float x) {
  union { float f; unsigned u; } v; v.f = x;
  return (v.u + 0x8000u) >> 16;
}
__device__ __forceinline__ float bf2f(unsigned short u) {
  union { unsigned u; float f; } v; v.u = ((unsigned)u) << 16;
  return v.f;
}

// all-reduce sum over the 16-lane DPP row -- VALU pipe, no LDS.
__device__ __forceinline__ float rowsum16(float v) {
  union { float f; int i; } a, t;
  a.f = v;
  t.i = __builtin_amdgcn_update_dpp(0, a.i, 0x128, 0xf, 0xf, true); a.f += t.f; // ror:8
  t.i = __builtin_amdgcn_update_dpp(0, a.i, 0x124, 0xf, 0xf, true); a.f += t.f; // ror:4
  t.i = __builtin_amdgcn_update_dpp(0, a.i, 0x122, 0xf, 0xf, true); a.f += t.f; // ror:2
  t.i = __builtin_amdgcn_update_dpp(0, a.i, 0x121, 0xf, 0xf, true); a.f += t.f; // ror:1
  return a.f;
}

// broadcast the value of each 16-lane group's leader (lane & 0x30) to the
// whole group: ds_swizzle BitMode, and_mask=0x10 (keeps bit4 within 32-half).
__device__ __forceinline__ float bcast16(float v) {
  union { float f; int i; } a; a.f = v;
  a.i = __builtin_amdgcn_ds_swizzle(a.i, 0x0010);
  return a.f;
}

// ---------------------------------------------------------------------------
// K01: merged prep kernel (single launch). Unchanged (proven).
//  blocks [0,1600)    : k1 -- ConditionGeneration+perm+phi_2 -> exp(w)^T bf16
//  blocks [1600,1702) : k0 -- fragment-pack Bf / W1f / W2f (identity k-map)
//  blocks [1702,1705) : zero d_out
// ---------------------------------------------------------------------------
__global__ __launch_bounds__(256) void k01_prep(
    const float* __restrict__ x, const float* __restrict__ w1,
    const float* __restrict__ b1, const int* __restrict__ perm,
    const float* __restrict__ gn1w, const float* __restrict__ gn1b,
    const float* __restrict__ c2w, const float* __restrict__ c2b,
    const float* __restrict__ gn2w, const float* __restrict__ gn2b,
    const float* __restrict__ c3w, const float* __restrict__ c3b,
    const float* __restrict__ E, const int* __restrict__ swr,
    const float* __restrict__ fc1w, const float* __restrict__ fc2w,
    unsigned short* __restrict__ wT,
    unsigned short* __restrict__ Bf, unsigned short* __restrict__ W1f,
    unsigned short* __restrict__ W2f, float* __restrict__ out)
{
  __shared__ float xl[64 * NCOL];          // k1 path only (25.6 KB)
  __shared__ int ridx[NEST];               // k0 path only
  const int tid = threadIdx.x;
  const int blk = blockIdx.x;

  if (blk < 1600) {
    // ---------------- k1: phi_2 logits -> exp -> bf16, transposed ----------
    const int b0 = (blk & 63) * 64;
    const int g  = (blk >> 6) * 64 + (tid >> 2);
    const int i4 = tid & 3;
    for (int i = tid; i < 64 * NCOL; i += 256)
      xl[i] = x[(size_t)b0 * NCOL + i];
    __syncthreads();

    const int4 p4 = *(const int4*)(perm + 4 * g);
    const int pv[4] = {p4.x, p4.y, p4.z, p4.w};
    float w1v[4], b1v[4];
    int pc[4];
#pragma unroll
    for (int i = 0; i < 4; i++) {
      unsigned p = (unsigned)pv[i];
      unsigned j = p / 100u;
      unsigned cc = p - j * 100u;
      pc[i] = (int)cc;
      w1v[i] = w1[cc * NCOND + j];
      b1v[i] = b1[cc * NCOND + j];
    }
    const float4 g1w = *(const float4*)(gn1w + 4 * g);
    const float4 g1b = *(const float4*)(gn1b + 4 * g);
    const float4 cw0 = *(const float4*)(c2w + 16 * g);
    const float4 cw1 = *(const float4*)(c2w + 16 * g + 4);
    const float4 cw2 = *(const float4*)(c2w + 16 * g + 8);
    const float4 cw3 = *(const float4*)(c2w + 16 * g + 12);
    const float4 cbv = *(const float4*)(c2b + 4 * g);
    const float4 g2w = *(const float4*)(gn2w + 4 * g);
    const float4 g2b = *(const float4*)(gn2b + 4 * g);
    const float4 c3v = *(const float4*)(c3w + 4 * g);
    const float c3bv = c3b[g];

    for (int k = 0; k < 4; k++) {
      float v4[4];
#pragma unroll
      for (int j = 0; j < 4; j++) {
        const int bb = k * 16 + i4 * 4 + j;
        float O[4];
#pragma unroll
        for (int i = 0; i < 4; i++) {
          float a = xl[bb * NCOL + pc[i]] * w1v[i] + b1v[i];
          O[i] = 1.0f / (1.0f + __expf(-a));
        }
        float mu = 0.25f * (O[0] + O[1] + O[2] + O[3]);
        float d[4], var = 0.f;
#pragma unroll
        for (int i = 0; i < 4; i++) { d[i] = O[i] - mu; var += d[i] * d[i]; }
        float rs = rsqrtf(0.25f * var + GEPS);
        float xn0 = d[0] * rs * g1w.x + g1b.x;
        float xn1 = d[1] * rs * g1w.y + g1b.y;
        float xn2 = d[2] * rs * g1w.z + g1b.z;
        float xn3 = d[3] * rs * g1w.w + g1b.w;
        float h[4];
        h[0] = xn0*cw0.x + xn1*cw1.x + xn2*cw2.x + xn3*cw3.x + cbv.x;
        h[1] = xn0*cw0.y + xn1*cw1.y + xn2*cw2.y + xn3*cw3.y + cbv.y;
        h[2] = xn0*cw0.z + xn1*cw1.z + xn2*cw2.z + xn3*cw3.z + cbv.z;
        h[3] = xn0*cw0.w + xn1*cw1.w + xn2*cw2.w + xn3*cw3.w + cbv.w;
#pragma unroll
        for (int i = 0; i < 4; i++) h[i] = fmaxf(h[i], 0.f);
        float mu2 = 0.25f * (h[0] + h[1] + h[2] + h[3]);
        float e[4], var2 = 0.f;
#pragma unroll
        for (int i = 0; i < 4; i++) { e[i] = h[i] - mu2; var2 += e[i] * e[i]; }
        float rs2 = rsqrtf(0.25f * var2 + GEPS);
        float hn0 = e[0] * rs2 * g2w.x + g2b.x;
        float hn1 = e[1] * rs2 * g2w.y + g2b.y;
        float hn2 = e[2] * rs2 * g2w.z + g2b.z;
        float hn3 = e[3] * rs2 * g2w.w + g2b.w;
        v4[j] = hn0*c3v.x + hn1*c3v.y + hn2*c3v.z + hn3*c3v.w + c3bv;
      }
      // store exp(logit): k3's softmax numerator, once per unique (g,b)
      uint2 pk;
      pk.x = f2bfu(__expf(v4[0])) | (f2bfu(__expf(v4[1])) << 16);
      pk.y = f2bfu(__expf(v4[2])) | (f2bfu(__expf(v4[3])) << 16);
      *(uint2*)(wT + (size_t)g * NB + b0 + k * 16 + i4 * 4) = pk;
    }
  } else if (blk < 1600 + NFOR) {
    // ---------------- k0: Bf fragment pack ----------------
    const int fblk = blk - 1600;
    if (tid < NEST) ridx[tid] = swr[fblk * NEST + tid];
    __syncthreads();
    for (int m = tid; m < 2560; m += 256) {        // m = (n*5+kc)*64 + lane
      int lane = m & 63, rest = m >> 6;
      int kc = rest % 5, n = rest / 5;
      int q = lane >> 4, c = lane & 15;
      int e0 = kc * 32 + q * 8;
      int h = n * 16 + c;
      union { unsigned short v[8]; uint4 u; } t;
#pragma unroll
      for (int j = 0; j < 8; j++)
        t.v[j] = (unsigned short)f2bfu(E[(size_t)ridx[e0 + j] * NHID + h]);
      *(uint4*)(Bf + (size_t)fblk * 20480 + (size_t)m * 8) = t.u;
    }
  } else if (blk == 1600 + NFOR) {
    // ---------------- k0: W1f (identity k-map) ----------------
    for (int m = tid; m < 2048; m += 256) {        // m = (n*4+kc)*64 + lane
      int lane = m & 63, rest = m >> 6;
      int kc = rest & 3, n = rest >> 2;
      int q = lane >> 4, c = lane & 15;
      int k0 = kc * 32 + q * 8;
      int o = n * 16 + c;
      union { unsigned short v[8]; uint4 u; } t;
#pragma unroll
      for (int j = 0; j < 8; j++)
        t.v[j] = (unsigned short)f2bfu(fc1w[(size_t)(k0 + j) * NHID + o]);
      *(uint4*)(W1f + (size_t)m * 8) = t.u;
    }
  } else if (blk == 1601 + NFOR) {
    // ---------------- k0: W2f (identity k-map) ----------------
    for (int m = tid; m < 256; m += 256) {         // m = kc*64 + lane
      int lane = m & 63, kc = m >> 6;
      int q = lane >> 4, c = lane & 15;
      int k0 = kc * 32 + q * 8;
      union { unsigned short v[8]; uint4 u; } t;
#pragma unroll
      for (int j = 0; j < 8; j++)
        t.v[j] = (unsigned short)f2bfu(c < NCLS ? fc2w[(size_t)(k0 + j) * NCLS + c] : 0.f);
      *(uint4*)(W2f + (size_t)m * 8) = t.u;
    }
  } else {
    // ---------------- zero d_out (3 blocks) ----------------
    const int z = blk - (1602 + NFOR);
    float4 zz = make_float4(0.f, 0.f, 0.f, 0.f);
    for (int i = z * 256 + tid; i < NB * NCLS / 4; i += 3 * 256)
      ((float4*)out)[i] = zz;
  }
}

// ---------------------------------------------------------------------------
// K3 (R22): M=128 2-tile pipeline (R21, proven) + three VALU/latency cuts:
//  1. softmax denominator via MFMA-ones column: GEMM1 gets a per-kc MFMA
//     against a B-fragment that is 1.0 in col 0 only -> D[row][0] = full
//     160-wide sum of exp. Broadcast col0 to the 16-lane row via ds_swizzle
//     (BitMode and=0x10). Replaces ~320 VALU ssum ops + the sPT LDS buffer.
//  2. gather in 2x20-index chunks (40 loads in flight) -- indices are
//     wave-uniform SGPRs, so depth costs only dest VGPRs, which are FREE
//     under the 3-block LDS occupancy cap (VGPR budget ~170).
//  3. Bf kc=0 fragments prefetched before the barrier.
//  Straight-line body, statically-indexed register arrays only (R18 lesson).
// ---------------------------------------------------------------------------
__global__ __launch_bounds__(256, 3) void k3_mfma(
    const unsigned short* __restrict__ wT,    // [1600][B] bf16 exp(logits)^T
    const int* __restrict__ swr,
    const unsigned short* __restrict__ Bf,    // [f][8][5][64][8]
    const unsigned short* __restrict__ W1f,   // [8][4][64][8]
    const unsigned short* __restrict__ W2f,   // [4][64][8]
    const float* __restrict__ ln1w, const float* __restrict__ ln1b,
    const float* __restrict__ fc1b,
    const float* __restrict__ ln2w, const float* __restrict__ ln2b,
    const float* __restrict__ fc2b,
    float* __restrict__ out)
{
  __shared__ unsigned short lsA[128 * 168];   // 43008 B (rows 0-63 t0, 64-127 t1)

  const int tid = threadIdx.x;
  const int b0 = blockIdx.x * 128;
  const int f  = blockIdx.y;
  const int lane = tid & 63;
  const int wv = __builtin_amdgcn_readfirstlane(tid >> 6);  // wave-uniform SGPR
  const int c = lane & 15, q = lane >> 4;

  // ---- gather phase: wave wv covers e in [40wv,40wv+40) for BOTH tiles ----
  // 2 chunks of 20 indices; all indices hoisted (wave-uniform -> s_load).
  {
    const unsigned short* wbase = wT + b0 + lane;
    const int* swf = swr + f * NEST + wv * 40;
    int idx[40];
#pragma unroll
    for (int e = 0; e < 40; e++) idx[e] = swf[e];

    unsigned short* r0 = lsA + lane * 168 + wv * 40;
    unsigned short* r1 = r0 + 64 * 168;

#pragma unroll
    for (int h = 0; h < 2; h++) {
      unsigned short u0[20], u1[20];
#pragma unroll
      for (int e = 0; e < 20; e++) {
        const unsigned short* p = wbase + (size_t)idx[h * 20 + e] * NB;
        u0[e] = p[0];
        u1[e] = p[64];
      }
      // pack & store shorts [20h, 20h+20) of rows lane (t0) / lane+64 (t1)
#define MKU(a, i) ((unsigned)(a)[i] | ((unsigned)(a)[i + 1] << 16))
      if (h == 0) {
        uint4 a0 = {MKU(u0,0), MKU(u0,2), MKU(u0,4), MKU(u0,6)};
        uint4 b0v = {MKU(u0,8), MKU(u0,10), MKU(u0,12), MKU(u0,14)};
        uint2 c0 = {MKU(u0,16), MKU(u0,18)};
        *(uint4*)(r0 + 0) = a0;  *(uint4*)(r0 + 8) = b0v;  *(uint2*)(r0 + 16) = c0;
        uint4 a1 = {MKU(u1,0), MKU(u1,2), MKU(u1,4), MKU(u1,6)};
        uint4 b1v = {MKU(u1,8), MKU(u1,10), MKU(u1,12), MKU(u1,14)};
        uint2 c1 = {MKU(u1,16), MKU(u1,18)};
        *(uint4*)(r1 + 0) = a1;  *(uint4*)(r1 + 8) = b1v;  *(uint2*)(r1 + 16) = c1;
      } else {
        uint2 a0 = {MKU(u0,0), MKU(u0,2)};
        uint4 b0v = {MKU(u0,4), MKU(u0,6), MKU(u0,8), MKU(u0,10)};
        uint4 c0 = {MKU(u0,12), MKU(u0,14), MKU(u0,16), MKU(u0,18)};
        *(uint2*)(r0 + 20) = a0;  *(uint4*)(r0 + 24) = b0v;  *(uint4*)(r0 + 32) = c0;
        uint2 a1 = {MKU(u1,0), MKU(u1,2)};
        uint4 b1v = {MKU(u1,4), MKU(u1,6), MKU(u1,8), MKU(u1,10)};
        uint4 c1 = {MKU(u1,12), MKU(u1,14), MKU(u1,16), MKU(u1,18)};
        *(uint2*)(r1 + 20) = a1;  *(uint4*)(r1 + 24) = b1v;  *(uint4*)(r1 + 32) = c1;
      }
#undef MKU
    }
  }

  // ---- prefetch GEMM1 kc=0 B-fragments (independent of gather/barrier) ----
  const unsigned short* bbase = Bf + (size_t)f * 20480 + lane * 8;
  short8 bp[8];
#pragma unroll
  for (int n = 0; n < 8; n++)
    bp[n] = *(const short8*)(bbase + n * 2560);

  __syncthreads();                     // the ONLY barrier

  // ---- GEMM1: (exp-ws)[128x160] @ Ep[160x128]; B loaded once per 2 tiles --
  //      + ones-column MFMA computing the softmax denominators
  const unsigned short* pa0 = lsA + (wv * 16 + c) * 168 + q * 8;
  const unsigned short* pa1 = pa0 + 64 * 168;
  const short onev = (c == 0) ? (short)0x3F80 : (short)0;  // bf16 1.0 in col 0
  short8 bones;
#pragma unroll
  for (int j = 0; j < 8; j++) bones[j] = onev;

  floatx4 acc0[8], acc1[8];
  floatx4 accs0 = (floatx4){0.f, 0.f, 0.f, 0.f};
  floatx4 accs1 = (floatx4){0.f, 0.f, 0.f, 0.f};
  {
    short8 a0 = *(const short8*)(pa0);
    short8 a1 = *(const short8*)(pa1);
#pragma unroll
    for (int n = 0; n < 8; n++) {
      acc0[n] = __builtin_amdgcn_mfma_f32_16x16x32_bf16(a0, bp[n], (floatx4){0.f,0.f,0.f,0.f}, 0, 0, 0);
      acc1[n] = __builtin_amdgcn_mfma_f32_16x16x32_bf16(a1, bp[n], (floatx4){0.f,0.f,0.f,0.f}, 0, 0, 0);
    }
    accs0 = __builtin_amdgcn_mfma_f32_16x16x32_bf16(a0, bones, accs0, 0, 0, 0);
    accs1 = __builtin_amdgcn_mfma_f32_16x16x32_bf16(a1, bones, accs1, 0, 0, 0);
  }
#pragma unroll
  for (int kc = 1; kc < 5; kc++) {
    short8 a0 = *(const short8*)(pa0 + kc * 32);
    short8 a1 = *(const short8*)(pa1 + kc * 32);
#pragma unroll
    for (int n = 0; n < 8; n++) {
      short8 b = *(const short8*)(bbase + n * 2560 + kc * 512);
      acc0[n] = __builtin_amdgcn_mfma_f32_16x16x32_bf16(a0, b, acc0[n], 0, 0, 0);
      acc1[n] = __builtin_amdgcn_mfma_f32_16x16x32_bf16(a1, b, acc1[n], 0, 0, 0);
    }
    accs0 = __builtin_amdgcn_mfma_f32_16x16x32_bf16(a0, bones, accs0, 0, 0, 0);
    accs1 = __builtin_amdgcn_mfma_f32_16x16x32_bf16(a1, bones, accs1, 0, 0, 0);
  }

  // ---- LN1 (both tiles): LN(x/s) == (x-mu)*rsqrt(var + eps*s^2) ----
  {
    float lw[8], lb[8];
#pragma unroll
    for (int n = 0; n < 8; n++) { lw[n] = ln1w[n * 16 + c]; lb[n] = ln1b[n * 16 + c]; }
#pragma unroll
    for (int rr = 0; rr < 4; rr++) {
      {
        float st = bcast16(accs0[rr]);         // denominator, row q*4+rr (t0)
        float s1 = 0.f, s2 = 0.f;
#pragma unroll
        for (int n = 0; n < 8; n++) { float v = acc0[n][rr]; s1 += v; s2 += v * v; }
        s1 = rowsum16(s1);
        s2 = rowsum16(s2);
        float mu = s1 * (1.f / 128.f);
        float var = fmaxf(s2 * (1.f / 128.f) - mu * mu, 0.f);
        float rs = rsqrtf(var + GEPS * st * st);
#pragma unroll
        for (int n = 0; n < 8; n++)
          acc0[n][rr] = (acc0[n][rr] - mu) * rs * lw[n] + lb[n];
      }
      {
        float st = bcast16(accs1[rr]);         // denominator, row q*4+rr (t1)
        float s1 = 0.f, s2 = 0.f;
#pragma unroll
        for (int n = 0; n < 8; n++) { float v = acc1[n][rr]; s1 += v; s2 += v * v; }
        s1 = rowsum16(s1);
        s2 = rowsum16(s2);
        float mu = s1 * (1.f / 128.f);
        float var = fmaxf(s2 * (1.f / 128.f) - mu * mu, 0.f);
        float rs = rsqrtf(var + GEPS * st * st);
#pragma unroll
        for (int n = 0; n < 8; n++)
          acc1[n][rr] = (acc1[n][rr] - mu) * rs * lw[n] + lb[n];
      }
    }
  }

  // ---- Fn -> lsA (A-layout bf16, wave-private rows; no barrier needed) ----
#pragma unroll
  for (int rr = 0; rr < 4; rr++)
#pragma unroll
    for (int n = 0; n < 8; n++) {
      lsA[(wv * 16 + q * 4 + rr) * 168 + n * 16 + c] =
          (unsigned short)f2bfu(acc0[n][rr]);
      lsA[(64 + wv * 16 + q * 4 + rr) * 168 + n * 16 + c] =
          (unsigned short)f2bfu(acc1[n][rr]);
    }

  // ---- GEMM2: H = Fn[128x128] @ fc1w[128x128]; W1f loaded once per 2 tiles -
  {
    short8 a00 = *(const short8*)(pa0);
    short8 a01 = *(const short8*)(pa0 + 32);
    short8 a02 = *(const short8*)(pa0 + 64);
    short8 a03 = *(const short8*)(pa0 + 96);
    short8 a10 = *(const short8*)(pa1);
    short8 a11 = *(const short8*)(pa1 + 32);
    short8 a12 = *(const short8*)(pa1 + 64);
    short8 a13 = *(const short8*)(pa1 + 96);
    const unsigned short* w1p = W1f + lane * 8;
#pragma unroll
    for (int n = 0; n < 8; n++) {
      const unsigned short* wp = w1p + n * 2048;
      short8 b0v = *(const short8*)(wp);
      short8 b1v = *(const short8*)(wp + 512);
      short8 b2v = *(const short8*)(wp + 1024);
      short8 b3v = *(const short8*)(wp + 1536);
      floatx4 t0 = __builtin_amdgcn_mfma_f32_16x16x32_bf16(a00, b0v, (floatx4){0.f,0.f,0.f,0.f}, 0, 0, 0);
      t0 = __builtin_amdgcn_mfma_f32_16x16x32_bf16(a01, b1v, t0, 0, 0, 0);
      t0 = __builtin_amdgcn_mfma_f32_16x16x32_bf16(a02, b2v, t0, 0, 0, 0);
      t0 = __builtin_amdgcn_mfma_f32_16x16x32_bf16(a03, b3v, t0, 0, 0, 0);
      floatx4 t1 = __builtin_amdgcn_mfma_f32_16x16x32_bf16(a10, b0v, (floatx4){0.f,0.f,0.f,0.f}, 0, 0, 0);
      t1 = __builtin_amdgcn_mfma_f32_16x16x32_bf16(a11, b1v, t1, 0, 0, 0);
      t1 = __builtin_amdgcn_mfma_f32_16x16x32_bf16(a12, b2v, t1, 0, 0, 0);
      t1 = __builtin_amdgcn_mfma_f32_16x16x32_bf16(a13, b3v, t1, 0, 0, 0);
      acc0[n] = t0;
      acc1[n] = t1;
    }
  }

  // ---- bias + ReLU + LN2 (both tiles, DPP row-reduce) ----
  {
    float fb[8], lw[8], lb[8];
#pragma unroll
    for (int n = 0; n < 8; n++) {
      fb[n] = fc1b[n * 16 + c];
      lw[n] = ln2w[n * 16 + c]; lb[n] = ln2b[n * 16 + c];
    }
#pragma unroll
    for (int rr = 0; rr < 4; rr++) {
      {
#pragma unroll
        for (int n = 0; n < 8; n++) acc0[n][rr] = fmaxf(acc0[n][rr] + fb[n], 0.f);
        float s1 = 0.f, s2 = 0.f;
#pragma unroll
        for (int n = 0; n < 8; n++) { float v = acc0[n][rr]; s1 += v; s2 += v * v; }
        s1 = rowsum16(s1);
        s2 = rowsum16(s2);
        float mu = s1 * (1.f / 128.f);
        float var = fmaxf(s2 * (1.f / 128.f) - mu * mu, 0.f);
        float rs = rsqrtf(var + GEPS);
#pragma unroll
        for (int n = 0; n < 8; n++)
          acc0[n][rr] = (acc0[n][rr] - mu) * rs * lw[n] + lb[n];
      }
      {
#pragma unroll
        for (int n = 0; n < 8; n++) acc1[n][rr] = fmaxf(acc1[n][rr] + fb[n], 0.f);
        float s1 = 0.f, s2 = 0.f;
#pragma unroll
        for (int n = 0; n < 8; n++) { float v = acc1[n][rr]; s1 += v; s2 += v * v; }
        s1 = rowsum16(s1);
        s2 = rowsum16(s2);
        float mu = s1 * (1.f / 128.f);
        float var = fmaxf(s2 * (1.f / 128.f) - mu * mu, 0.f);
        float rs = rsqrtf(var + GEPS);
#pragma unroll
        for (int n = 0; n < 8; n++)
          acc1[n][rr] = (acc1[n][rr] - mu) * rs * lw[n] + lb[n];
      }
    }
  }

  // ---- H2 -> lsA (A-layout, wave-private rows; no barrier) ----
#pragma unroll
  for (int rr = 0; rr < 4; rr++)
#pragma unroll
    for (int n = 0; n < 8; n++) {
      lsA[(wv * 16 + q * 4 + rr) * 168 + n * 16 + c] =
          (unsigned short)f2bfu(acc0[n][rr]);
      lsA[(64 + wv * 16 + q * 4 + rr) * 168 + n * 16 + c] =
          (unsigned short)f2bfu(acc1[n][rr]);
    }

  // ---- fc2 (16-col padded tile), W2f loaded once per 2 tiles ----
  floatx4 o40 = (floatx4){0.f, 0.f, 0.f, 0.f};
  floatx4 o41 = (floatx4){0.f, 0.f, 0.f, 0.f};
#pragma unroll
  for (int kc = 0; kc < 4; kc++) {
    short8 a0 = *(const short8*)(pa0 + kc * 32);
    short8 a1 = *(const short8*)(pa1 + kc * 32);
    short8 b = *(const short8*)(W2f + kc * 512 + lane * 8);
    o40 = __builtin_amdgcn_mfma_f32_16x16x32_bf16(a0, b, o40, 0, 0, 0);
    o41 = __builtin_amdgcn_mfma_f32_16x16x32_bf16(a1, b, o41, 0, 0, 0);
  }
  if (c < NCLS) {
    float bias = fc2b[c];
#pragma unroll
    for (int rr = 0; rr < 4; rr++) {
      atomicAdd(out + (size_t)(b0 + wv * 16 + q * 4 + rr) * NCLS + c,
                (o40[rr] + bias) * 0.01f);
      atomicAdd(out + (size_t)(b0 + 64 + wv * 16 + q * 4 + rr) * NCLS + c,
                (o41[rr] + bias) * 0.01f);
    }
  }
}

// ---------------------------------------------------------------------------
extern "C" void kernel_launch(void* const* d_in, const int* in_sizes, int n_in,
                              void* d_out, int out_size, void* d_ws, size_t ws_size,
                              hipStream_t stream)
{
  (void)in_sizes; (void)n_in; (void)ws_size; (void)out_size;
  const float* x    = (const float*)d_in[0];
  const float* w1   = (const float*)d_in[1];
  const float* b1   = (const float*)d_in[2];
  const int*   perm = (const int*)d_in[3];
  const float* gn1w = (const float*)d_in[4];
  const float* gn1b = (const float*)d_in[5];
  const float* c2w  = (const float*)d_in[6];
  const float* c2b  = (const float*)d_in[7];
  const float* gn2w = (const float*)d_in[8];
  const float* gn2b = (const float*)d_in[9];
  const float* c3w  = (const float*)d_in[10];
  const float* c3b  = (const float*)d_in[11];
  const int*   swr  = (const int*)d_in[12];
  const float* E    = (const float*)d_in[13];
  const float* ln1w = (const float*)d_in[14];
  const float* ln1b = (const float*)d_in[15];
  const float* fc1w = (const float*)d_in[16];
  const float* fc1b = (const float*)d_in[17];
  const float* ln2w = (const float*)d_in[18];
  const float* ln2b = (const float*)d_in[19];
  const float* fc2w = (const float*)d_in[20];
  const float* fc2b = (const float*)d_in[21];
  float* out = (float*)d_out;

  // workspace layout:
  //   [0, 13.1MB)       : wT exp-logits bf16 [1600][B]
  //   [13.1MB, +4.10MB) : Bf (100*20480 shorts)
  //   then W1f 32,768 B, W2f 4,096 B
  const size_t W_BYTES = (size_t)NB * NRODT * 2;     // 13,107,200
  unsigned short* wTbuf = (unsigned short*)d_ws;
  unsigned short* Bfb   = (unsigned short*)((char*)d_ws + W_BYTES);
  unsigned short* W1fb  = (unsigned short*)((char*)d_ws + W_BYTES + 4096000);
  unsigned short* W2fb  = (unsigned short*)((char*)d_ws + W_BYTES + 4096000 + 32768);

  k01_prep<<<1600 + NFOR + 2 + 3, 256, 0, stream>>>(
      x, w1, b1, perm, gn1w, gn1b, c2w, c2b, gn2w, gn2b, c3w, c3b,
      E, swr, fc1w, fc2w, wTbuf, Bfb, W1fb, W2fb, out);
  dim3 g3(NB / 128, NFOR);
  k3_mfma<<<g3, 256, 0, stream>>>(wTbuf, swr, Bfb, W1fb, W2fb,
                                  ln1w, ln1b, fc1b, ln2w, ln2b, fc2b, out);
}

// Round 6
// 206.584 us; speedup vs baseline: 1.0800x; 1.0130x over previous
//
#include <hip/hip_runtime.h>
#include <hip/hip_bf16.h>
#include <stdint.h>

#define NB 4096
#define NCOL 100
#define NCOND 64
#define NTOTAL 6400
#define NRODT 1600
#define NEST 160
#define NFOR 100
#define NHID 128
#define NCLS 10
#define GEPS 1e-5f

typedef __attribute__((ext_vector_type(8))) short short8;
typedef __attribute__((ext_vector_type(4))) float floatx4;

// round-half-up f32->bf16: 2 VALU ops; tie-only difference vs RNE
__device__ __forceinline__ unsigned f2bfu(float x) {
  union { float f; unsigned u; } v; v.f = x;
  return (v.u + 0x8000u) >> 16;
}
__device__ __forceinline__ float bf2f(unsigned short u) {
  union { unsigned u; float f; } v; v.u = ((unsigned)u) << 16;
  return v.f;
}

// all-reduce sum over the 16-lane DPP row -- VALU pipe, no LDS.
__device__ __forceinline__ float rowsum16(float v) {
  union { float f; int i; } a, t;
  a.f = v;
  t.i = __builtin_amdgcn_update_dpp(0, a.i, 0x128, 0xf, 0xf, true); a.f += t.f; // ror:8
  t.i = __builtin_amdgcn_update_dpp(0, a.i, 0x124, 0xf, 0xf, true); a.f += t.f; // ror:4
  t.i = __builtin_amdgcn_update_dpp(0, a.i, 0x122, 0xf, 0xf, true); a.f += t.f; // ror:2
  t.i = __builtin_amdgcn_update_dpp(0, a.i, 0x121, 0xf, 0xf, true); a.f += t.f; // ror:1
  return a.f;
}

// broadcast the value of each 16-lane group's leader (lane & 0x30) to the
// whole group: ds_swizzle BitMode, and_mask=0x10 (keeps bit4 within 32-half).
__device__ __forceinline__ float bcast16(float v) {
  union { float f; int i; } a; a.f = v;
  a.i = __builtin_amdgcn_ds_swizzle(a.i, 0x0010);
  return a.f;
}

// ---------------------------------------------------------------------------
// K01: merged prep kernel (single launch). Unchanged (proven).
//  blocks [0,1600)    : k1 -- ConditionGeneration+perm+phi_2 -> exp(w)^T bf16
//  blocks [1600,1702) : k0 -- fragment-pack Bf / W1f / W2f (identity k-map)
//  blocks [1702,1705) : zero d_out
// ---------------------------------------------------------------------------
__global__ __launch_bounds__(256) void k01_prep(
    const float* __restrict__ x, const float* __restrict__ w1,
    const float* __restrict__ b1, const int* __restrict__ perm,
    const float* __restrict__ gn1w, const float* __restrict__ gn1b,
    const float* __restrict__ c2w, const float* __restrict__ c2b,
    const float* __restrict__ gn2w, const float* __restrict__ gn2b,
    const float* __restrict__ c3w, const float* __restrict__ c3b,
    const float* __restrict__ E, const int* __restrict__ swr,
    const float* __restrict__ fc1w, const float* __restrict__ fc2w,
    unsigned short* __restrict__ wT,
    unsigned short* __restrict__ Bf, unsigned short* __restrict__ W1f,
    unsigned short* __restrict__ W2f, float* __restrict__ out)
{
  __shared__ float xl[64 * NCOL];          // k1 path only (25.6 KB)
  __shared__ int ridx[NEST];               // k0 path only
  const int tid = threadIdx.x;
  const int blk = blockIdx.x;

  if (blk < 1600) {
    // ---------------- k1: phi_2 logits -> exp -> bf16, transposed ----------
    const int b0 = (blk & 63) * 64;
    const int g  = (blk >> 6) * 64 + (tid >> 2);
    const int i4 = tid & 3;
    for (int i = tid; i < 64 * NCOL; i += 256)
      xl[i] = x[(size_t)b0 * NCOL + i];
    __syncthreads();

    const int4 p4 = *(const int4*)(perm + 4 * g);
    const int pv[4] = {p4.x, p4.y, p4.z, p4.w};
    float w1v[4], b1v[4];
    int pc[4];
#pragma unroll
    for (int i = 0; i < 4; i++) {
      unsigned p = (unsigned)pv[i];
      unsigned j = p / 100u;
      unsigned cc = p - j * 100u;
      pc[i] = (int)cc;
      w1v[i] = w1[cc * NCOND + j];
      b1v[i] = b1[cc * NCOND + j];
    }
    const float4 g1w = *(const float4*)(gn1w + 4 * g);
    const float4 g1b = *(const float4*)(gn1b + 4 * g);
    const float4 cw0 = *(const float4*)(c2w + 16 * g);
    const float4 cw1 = *(const float4*)(c2w + 16 * g + 4);
    const float4 cw2 = *(const float4*)(c2w + 16 * g + 8);
    const float4 cw3 = *(const float4*)(c2w + 16 * g + 12);
    const float4 cbv = *(const float4*)(c2b + 4 * g);
    const float4 g2w = *(const float4*)(gn2w + 4 * g);
    const float4 g2b = *(const float4*)(gn2b + 4 * g);
    const float4 c3v = *(const float4*)(c3w + 4 * g);
    const float c3bv = c3b[g];

    for (int k = 0; k < 4; k++) {
      float v4[4];
#pragma unroll
      for (int j = 0; j < 4; j++) {
        const int bb = k * 16 + i4 * 4 + j;
        float O[4];
#pragma unroll
        for (int i = 0; i < 4; i++) {
          float a = xl[bb * NCOL + pc[i]] * w1v[i] + b1v[i];
          O[i] = 1.0f / (1.0f + __expf(-a));
        }
        float mu = 0.25f * (O[0] + O[1] + O[2] + O[3]);
        float d[4], var = 0.f;
#pragma unroll
        for (int i = 0; i < 4; i++) { d[i] = O[i] - mu; var += d[i] * d[i]; }
        float rs = rsqrtf(0.25f * var + GEPS);
        float xn0 = d[0] * rs * g1w.x + g1b.x;
        float xn1 = d[1] * rs * g1w.y + g1b.y;
        float xn2 = d[2] * rs * g1w.z + g1b.z;
        float xn3 = d[3] * rs * g1w.w + g1b.w;
        float h[4];
        h[0] = xn0*cw0.x + xn1*cw1.x + xn2*cw2.x + xn3*cw3.x + cbv.x;
        h[1] = xn0*cw0.y + xn1*cw1.y + xn2*cw2.y + xn3*cw3.y + cbv.y;
        h[2] = xn0*cw0.z + xn1*cw1.z + xn2*cw2.z + xn3*cw3.z + cbv.z;
        h[3] = xn0*cw0.w + xn1*cw1.w + xn2*cw2.w + xn3*cw3.w + cbv.w;
#pragma unroll
        for (int i = 0; i < 4; i++) h[i] = fmaxf(h[i], 0.f);
        float mu2 = 0.25f * (h[0] + h[1] + h[2] + h[3]);
        float e[4], var2 = 0.f;
#pragma unroll
        for (int i = 0; i < 4; i++) { e[i] = h[i] - mu2; var2 += e[i] * e[i]; }
        float rs2 = rsqrtf(0.25f * var2 + GEPS);
        float hn0 = e[0] * rs2 * g2w.x + g2b.x;
        float hn1 = e[1] * rs2 * g2w.y + g2b.y;
        float hn2 = e[2] * rs2 * g2w.z + g2b.z;
        float hn3 = e[3] * rs2 * g2w.w + g2b.w;
        v4[j] = hn0*c3v.x + hn1*c3v.y + hn2*c3v.z + hn3*c3v.w + c3bv;
      }
      // store exp(logit): k3's softmax numerator, once per unique (g,b)
      uint2 pk;
      pk.x = f2bfu(__expf(v4[0])) | (f2bfu(__expf(v4[1])) << 16);
      pk.y = f2bfu(__expf(v4[2])) | (f2bfu(__expf(v4[3])) << 16);
      *(uint2*)(wT + (size_t)g * NB + b0 + k * 16 + i4 * 4) = pk;
    }
  } else if (blk < 1600 + NFOR) {
    // ---------------- k0: Bf fragment pack ----------------
    const int fblk = blk - 1600;
    if (tid < NEST) ridx[tid] = swr[fblk * NEST + tid];
    __syncthreads();
    for (int m = tid; m < 2560; m += 256) {        // m = (n*5+kc)*64 + lane
      int lane = m & 63, rest = m >> 6;
      int kc = rest % 5, n = rest / 5;
      int q = lane >> 4, c = lane & 15;
      int e0 = kc * 32 + q * 8;
      int h = n * 16 + c;
      union { unsigned short v[8]; uint4 u; } t;
#pragma unroll
      for (int j = 0; j < 8; j++)
        t.v[j] = (unsigned short)f2bfu(E[(size_t)ridx[e0 + j] * NHID + h]);
      *(uint4*)(Bf + (size_t)fblk * 20480 + (size_t)m * 8) = t.u;
    }
  } else if (blk == 1600 + NFOR) {
    // ---------------- k0: W1f (identity k-map) ----------------
    for (int m = tid; m < 2048; m += 256) {        // m = (n*4+kc)*64 + lane
      int lane = m & 63, rest = m >> 6;
      int kc = rest & 3, n = rest >> 2;
      int q = lane >> 4, c = lane & 15;
      int k0 = kc * 32 + q * 8;
      int o = n * 16 + c;
      union { unsigned short v[8]; uint4 u; } t;
#pragma unroll
      for (int j = 0; j < 8; j++)
        t.v[j] = (unsigned short)f2bfu(fc1w[(size_t)(k0 + j) * NHID + o]);
      *(uint4*)(W1f + (size_t)m * 8) = t.u;
    }
  } else if (blk == 1601 + NFOR) {
    // ---------------- k0: W2f (identity k-map) ----------------
    for (int m = tid; m < 256; m += 256) {         // m = kc*64 + lane
      int lane = m & 63, kc = m >> 6;
      int q = lane >> 4, c = lane & 15;
      int k0 = kc * 32 + q * 8;
      union { unsigned short v[8]; uint4 u; } t;
#pragma unroll
      for (int j = 0; j < 8; j++)
        t.v[j] = (unsigned short)f2bfu(c < NCLS ? fc2w[(size_t)(k0 + j) * NCLS + c] : 0.f);
      *(uint4*)(W2f + (size_t)m * 8) = t.u;
    }
  } else {
    // ---------------- zero d_out (3 blocks) ----------------
    const int z = blk - (1602 + NFOR);
    float4 zz = make_float4(0.f, 0.f, 0.f, 0.f);
    for (int i = z * 256 + tid; i < NB * NCLS / 4; i += 3 * 256)
      ((float4*)out)[i] = zz;
  }
}

// ---------------------------------------------------------------------------
// K3 (R23): R22 body + two latency levers:
//  1. XCD-chunked (bx,f) swizzle [T1]: 3200 blocks = 8 XCDs x 400. Default
//     round-robin gives each XCD a ~17 MB wT+Bf working set (L3-resident,
//     ~600cyc gather). Chunked: XCD x gets bx in [4x,4x+4), f sweeping with
//     4 consecutive blocks per f -> working set ~1.5 MB wT + ~1 MB Bf < 4 MB
//     L2 -> gather/Bf loads become L2 hits. 3200%8==0 -> bijective.
//  2. s_setprio(1) around the MFMA clusters [T5]: independent blocks on a CU
//     sit at different phases (gather vs GEMM) -> priority lets MFMA-phase
//     waves preempt gather-phase waves' issue slots.
//  Body otherwise identical to R22 (proven): straight-line, ones-column
//  denominator, 2x20-deep gather, kc0 Bf prefetch, one barrier.
// ---------------------------------------------------------------------------
__global__ __launch_bounds__(256, 3) void k3_mfma(
    const unsigned short* __restrict__ wT,    // [1600][B] bf16 exp(logits)^T
    const int* __restrict__ swr,
    const unsigned short* __restrict__ Bf,    // [f][8][5][64][8]
    const unsigned short* __restrict__ W1f,   // [8][4][64][8]
    const unsigned short* __restrict__ W2f,   // [4][64][8]
    const float* __restrict__ ln1w, const float* __restrict__ ln1b,
    const float* __restrict__ fc1b,
    const float* __restrict__ ln2w, const float* __restrict__ ln2b,
    const float* __restrict__ fc2b,
    float* __restrict__ out)
{
  __shared__ unsigned short lsA[128 * 168];   // 43008 B (rows 0-63 t0, 64-127 t1)

  const int tid = threadIdx.x;
  // ---- XCD-chunked swizzle: id -> (bx, f) ----
  const int id  = blockIdx.y * 32 + blockIdx.x;   // linear dispatch id, [0,3200)
  const int xcd = id & 7;
  const int pos = id >> 3;                        // [0,400)
  const int f   = pos >> 2;                       // [0,100)
  const int b0  = (xcd * 4 + (pos & 3)) * 128;    // bx in [4*xcd, 4*xcd+4)
  const int lane = tid & 63;
  const int wv = __builtin_amdgcn_readfirstlane(tid >> 6);  // wave-uniform SGPR
  const int c = lane & 15, q = lane >> 4;

  // ---- gather phase: wave wv covers e in [40wv,40wv+40) for BOTH tiles ----
  // 2 chunks of 20 indices; all indices hoisted (wave-uniform -> s_load).
  {
    const unsigned short* wbase = wT + b0 + lane;
    const int* swf = swr + f * NEST + wv * 40;
    int idx[40];
#pragma unroll
    for (int e = 0; e < 40; e++) idx[e] = swf[e];

    unsigned short* r0 = lsA + lane * 168 + wv * 40;
    unsigned short* r1 = r0 + 64 * 168;

#pragma unroll
    for (int h = 0; h < 2; h++) {
      unsigned short u0[20], u1[20];
#pragma unroll
      for (int e = 0; e < 20; e++) {
        const unsigned short* p = wbase + (size_t)idx[h * 20 + e] * NB;
        u0[e] = p[0];
        u1[e] = p[64];
      }
      // pack & store shorts [20h, 20h+20) of rows lane (t0) / lane+64 (t1)
#define MKU(a, i) ((unsigned)(a)[i] | ((unsigned)(a)[i + 1] << 16))
      if (h == 0) {
        uint4 a0 = {MKU(u0,0), MKU(u0,2), MKU(u0,4), MKU(u0,6)};
        uint4 b0v = {MKU(u0,8), MKU(u0,10), MKU(u0,12), MKU(u0,14)};
        uint2 c0 = {MKU(u0,16), MKU(u0,18)};
        *(uint4*)(r0 + 0) = a0;  *(uint4*)(r0 + 8) = b0v;  *(uint2*)(r0 + 16) = c0;
        uint4 a1 = {MKU(u1,0), MKU(u1,2), MKU(u1,4), MKU(u1,6)};
        uint4 b1v = {MKU(u1,8), MKU(u1,10), MKU(u1,12), MKU(u1,14)};
        uint2 c1 = {MKU(u1,16), MKU(u1,18)};
        *(uint4*)(r1 + 0) = a1;  *(uint4*)(r1 + 8) = b1v;  *(uint2*)(r1 + 16) = c1;
      } else {
        uint2 a0 = {MKU(u0,0), MKU(u0,2)};
        uint4 b0v = {MKU(u0,4), MKU(u0,6), MKU(u0,8), MKU(u0,10)};
        uint4 c0 = {MKU(u0,12), MKU(u0,14), MKU(u0,16), MKU(u0,18)};
        *(uint2*)(r0 + 20) = a0;  *(uint4*)(r0 + 24) = b0v;  *(uint4*)(r0 + 32) = c0;
        uint2 a1 = {MKU(u1,0), MKU(u1,2)};
        uint4 b1v = {MKU(u1,4), MKU(u1,6), MKU(u1,8), MKU(u1,10)};
        uint4 c1 = {MKU(u1,12), MKU(u1,14), MKU(u1,16), MKU(u1,18)};
        *(uint2*)(r1 + 20) = a1;  *(uint4*)(r1 + 24) = b1v;  *(uint4*)(r1 + 32) = c1;
      }
#undef MKU
    }
  }

  // ---- prefetch GEMM1 kc=0 B-fragments (independent of gather/barrier) ----
  const unsigned short* bbase = Bf + (size_t)f * 20480 + lane * 8;
  short8 bp[8];
#pragma unroll
  for (int n = 0; n < 8; n++)
    bp[n] = *(const short8*)(bbase + n * 2560);

  __syncthreads();                     // the ONLY barrier

  // ---- GEMM1: (exp-ws)[128x160] @ Ep[160x128]; B loaded once per 2 tiles --
  //      + ones-column MFMA computing the softmax denominators
  const unsigned short* pa0 = lsA + (wv * 16 + c) * 168 + q * 8;
  const unsigned short* pa1 = pa0 + 64 * 168;
  const short onev = (c == 0) ? (short)0x3F80 : (short)0;  // bf16 1.0 in col 0
  short8 bones;
#pragma unroll
  for (int j = 0; j < 8; j++) bones[j] = onev;

  floatx4 acc0[8], acc1[8];
  floatx4 accs0 = (floatx4){0.f, 0.f, 0.f, 0.f};
  floatx4 accs1 = (floatx4){0.f, 0.f, 0.f, 0.f};
  __builtin_amdgcn_s_setprio(1);
  {
    short8 a0 = *(const short8*)(pa0);
    short8 a1 = *(const short8*)(pa1);
#pragma unroll
    for (int n = 0; n < 8; n++) {
      acc0[n] = __builtin_amdgcn_mfma_f32_16x16x32_bf16(a0, bp[n], (floatx4){0.f,0.f,0.f,0.f}, 0, 0, 0);
      acc1[n] = __builtin_amdgcn_mfma_f32_16x16x32_bf16(a1, bp[n], (floatx4){0.f,0.f,0.f,0.f}, 0, 0, 0);
    }
    accs0 = __builtin_amdgcn_mfma_f32_16x16x32_bf16(a0, bones, accs0, 0, 0, 0);
    accs1 = __builtin_amdgcn_mfma_f32_16x16x32_bf16(a1, bones, accs1, 0, 0, 0);
  }
#pragma unroll
  for (int kc = 1; kc < 5; kc++) {
    short8 a0 = *(const short8*)(pa0 + kc * 32);
    short8 a1 = *(const short8*)(pa1 + kc * 32);
#pragma unroll
    for (int n = 0; n < 8; n++) {
      short8 b = *(const short8*)(bbase + n * 2560 + kc * 512);
      acc0[n] = __builtin_amdgcn_mfma_f32_16x16x32_bf16(a0, b, acc0[n], 0, 0, 0);
      acc1[n] = __builtin_amdgcn_mfma_f32_16x16x32_bf16(a1, b, acc1[n], 0, 0, 0);
    }
    accs0 = __builtin_amdgcn_mfma_f32_16x16x32_bf16(a0, bones, accs0, 0, 0, 0);
    accs1 = __builtin_amdgcn_mfma_f32_16x16x32_bf16(a1, bones, accs1, 0, 0, 0);
  }
  __builtin_amdgcn_s_setprio(0);

  // ---- LN1 (both tiles): LN(x/s) == (x-mu)*rsqrt(var + eps*s^2) ----
  {
    float lw[8], lb[8];
#pragma unroll
    for (int n = 0; n < 8; n++) { lw[n] = ln1w[n * 16 + c]; lb[n] = ln1b[n * 16 + c]; }
#pragma unroll
    for (int rr = 0; rr < 4; rr++) {
      {
        float st = bcast16(accs0[rr]);         // denominator, row q*4+rr (t0)
        float s1 = 0.f, s2 = 0.f;
#pragma unroll
        for (int n = 0; n < 8; n++) { float v = acc0[n][rr]; s1 += v; s2 += v * v; }
        s1 = rowsum16(s1);
        s2 = rowsum16(s2);
        float mu = s1 * (1.f / 128.f);
        float var = fmaxf(s2 * (1.f / 128.f) - mu * mu, 0.f);
        float rs = rsqrtf(var + GEPS * st * st);
#pragma unroll
        for (int n = 0; n < 8; n++)
          acc0[n][rr] = (acc0[n][rr] - mu) * rs * lw[n] + lb[n];
      }
      {
        float st = bcast16(accs1[rr]);         // denominator, row q*4+rr (t1)
        float s1 = 0.f, s2 = 0.f;
#pragma unroll
        for (int n = 0; n < 8; n++) { float v = acc1[n][rr]; s1 += v; s2 += v * v; }
        s1 = rowsum16(s1);
        s2 = rowsum16(s2);
        float mu = s1 * (1.f / 128.f);
        float var = fmaxf(s2 * (1.f / 128.f) - mu * mu, 0.f);
        float rs = rsqrtf(var + GEPS * st * st);
#pragma unroll
        for (int n = 0; n < 8; n++)
          acc1[n][rr] = (acc1[n][rr] - mu) * rs * lw[n] + lb[n];
      }
    }
  }

  // ---- Fn -> lsA (A-layout bf16, wave-private rows; no barrier needed) ----
#pragma unroll
  for (int rr = 0; rr < 4; rr++)
#pragma unroll
    for (int n = 0; n < 8; n++) {
      lsA[(wv * 16 + q * 4 + rr) * 168 + n * 16 + c] =
          (unsigned short)f2bfu(acc0[n][rr]);
      lsA[(64 + wv * 16 + q * 4 + rr) * 168 + n * 16 + c] =
          (unsigned short)f2bfu(acc1[n][rr]);
    }

  // ---- GEMM2: H = Fn[128x128] @ fc1w[128x128]; W1f loaded once per 2 tiles -
  {
    short8 a00 = *(const short8*)(pa0);
    short8 a01 = *(const short8*)(pa0 + 32);
    short8 a02 = *(const short8*)(pa0 + 64);
    short8 a03 = *(const short8*)(pa0 + 96);
    short8 a10 = *(const short8*)(pa1);
    short8 a11 = *(const short8*)(pa1 + 32);
    short8 a12 = *(const short8*)(pa1 + 64);
    short8 a13 = *(const short8*)(pa1 + 96);
    const unsigned short* w1p = W1f + lane * 8;
    __builtin_amdgcn_s_setprio(1);
#pragma unroll
    for (int n = 0; n < 8; n++) {
      const unsigned short* wp = w1p + n * 2048;
      short8 b0v = *(const short8*)(wp);
      short8 b1v = *(const short8*)(wp + 512);
      short8 b2v = *(const short8*)(wp + 1024);
      short8 b3v = *(const short8*)(wp + 1536);
      floatx4 t0 = __builtin_amdgcn_mfma_f32_16x16x32_bf16(a00, b0v, (floatx4){0.f,0.f,0.f,0.f}, 0, 0, 0);
      t0 = __builtin_amdgcn_mfma_f32_16x16x32_bf16(a01, b1v, t0, 0, 0, 0);
      t0 = __builtin_amdgcn_mfma_f32_16x16x32_bf16(a02, b2v, t0, 0, 0, 0);
      t0 = __builtin_amdgcn_mfma_f32_16x16x32_bf16(a03, b3v, t0, 0, 0, 0);
      floatx4 t1 = __builtin_amdgcn_mfma_f32_16x16x32_bf16(a10, b0v, (floatx4){0.f,0.f,0.f,0.f}, 0, 0, 0);
      t1 = __builtin_amdgcn_mfma_f32_16x16x32_bf16(a11, b1v, t1, 0, 0, 0);
      t1 = __builtin_amdgcn_mfma_f32_16x16x32_bf16(a12, b2v, t1, 0, 0, 0);
      t1 = __builtin_amdgcn_mfma_f32_16x16x32_bf16(a13, b3v, t1, 0, 0, 0);
      acc0[n] = t0;
      acc1[n] = t1;
    }
    __builtin_amdgcn_s_setprio(0);
  }

  // ---- bias + ReLU + LN2 (both tiles, DPP row-reduce) ----
  {
    float fb[8], lw[8], lb[8];
#pragma unroll
    for (int n = 0; n < 8; n++) {
      fb[n] = fc1b[n * 16 + c];
      lw[n] = ln2w[n * 16 + c]; lb[n] = ln2b[n * 16 + c];
    }
#pragma unroll
    for (int rr = 0; rr < 4; rr++) {
      {
#pragma unroll
        for (int n = 0; n < 8; n++) acc0[n][rr] = fmaxf(acc0[n][rr] + fb[n], 0.f);
        float s1 = 0.f, s2 = 0.f;
#pragma unroll
        for (int n = 0; n < 8; n++) { float v = acc0[n][rr]; s1 += v; s2 += v * v; }
        s1 = rowsum16(s1);
        s2 = rowsum16(s2);
        float mu = s1 * (1.f / 128.f);
        float var = fmaxf(s2 * (1.f / 128.f) - mu * mu, 0.f);
        float rs = rsqrtf(var + GEPS);
#pragma unroll
        for (int n = 0; n < 8; n++)
          acc0[n][rr] = (acc0[n][rr] - mu) * rs * lw[n] + lb[n];
      }
      {
#pragma unroll
        for (int n = 0; n < 8; n++) acc1[n][rr] = fmaxf(acc1[n][rr] + fb[n], 0.f);
        float s1 = 0.f, s2 = 0.f;
#pragma unroll
        for (int n = 0; n < 8; n++) { float v = acc1[n][rr]; s1 += v; s2 += v * v; }
        s1 = rowsum16(s1);
        s2 = rowsum16(s2);
        float mu = s1 * (1.f / 128.f);
        float var = fmaxf(s2 * (1.f / 128.f) - mu * mu, 0.f);
        float rs = rsqrtf(var + GEPS);
#pragma unroll
        for (int n = 0; n < 8; n++)
          acc1[n][rr] = (acc1[n][rr] - mu) * rs * lw[n] + lb[n];
      }
    }
  }

  // ---- H2 -> lsA (A-layout, wave-private rows; no barrier) ----
#pragma unroll
  for (int rr = 0; rr < 4; rr++)
#pragma unroll
    for (int n = 0; n < 8; n++) {
      lsA[(wv * 16 + q * 4 + rr) * 168 + n * 16 + c] =
          (unsigned short)f2bfu(acc0[n][rr]);
      lsA[(64 + wv * 16 + q * 4 + rr) * 168 + n * 16 + c] =
          (unsigned short)f2bfu(acc1[n][rr]);
    }

  // ---- fc2 (16-col padded tile), W2f loaded once per 2 tiles ----
  floatx4 o40 = (floatx4){0.f, 0.f, 0.f, 0.f};
  floatx4 o41 = (floatx4){0.f, 0.f, 0.f, 0.f};
#pragma unroll
  for (int kc = 0; kc < 4; kc++) {
    short8 a0 = *(const short8*)(pa0 + kc * 32);
    short8 a1 = *(const short8*)(pa1 + kc * 32);
    short8 b = *(const short8*)(W2f + kc * 512 + lane * 8);
    o40 = __builtin_amdgcn_mfma_f32_16x16x32_bf16(a0, b, o40, 0, 0, 0);
    o41 = __builtin_amdgcn_mfma_f32_16x16x32_bf16(a1, b, o41, 0, 0, 0);
  }
  if (c < NCLS) {
    float bias = fc2b[c];
#pragma unroll
    for (int rr = 0; rr < 4; rr++) {
      atomicAdd(out + (size_t)(b0 + wv * 16 + q * 4 + rr) * NCLS + c,
                (o40[rr] + bias) * 0.01f);
      atomicAdd(out + (size_t)(b0 + 64 + wv * 16 + q * 4 + rr) * NCLS + c,
                (o41[rr] + bias) * 0.01f);
    }
  }
}

// ---------------------------------------------------------------------------
extern "C" void kernel_launch(void* const* d_in, const int* in_sizes, int n_in,
                              void* d_out, int out_size, void* d_ws, size_t ws_size,
                              hipStream_t stream)
{
  (void)in_sizes; (void)n_in; (void)ws_size; (void)out_size;
  const float* x    = (const float*)d_in[0];
  const float* w1   = (const float*)d_in[1];
  const float* b1   = (const float*)d_in[2];
  const int*   perm = (const int*)d_in[3];
  const float* gn1w = (const float*)d_in[4];
  const float* gn1b = (const float*)d_in[5];
  const float* c2w  = (const float*)d_in[6];
  const float* c2b  = (const float*)d_in[7];
  const float* gn2w = (const float*)d_in[8];
  const float* gn2b = (const float*)d_in[9];
  const float* c3w  = (const float*)d_in[10];
  const float* c3b  = (const float*)d_in[11];
  const int*   swr  = (const int*)d_in[12];
  const float* E    = (const float*)d_in[13];
  const float* ln1w = (const float*)d_in[14];
  const float* ln1b = (const float*)d_in[15];
  const float* fc1w = (const float*)d_in[16];
  const float* fc1b = (const float*)d_in[17];
  const float* ln2w = (const float*)d_in[18];
  const float* ln2b = (const float*)d_in[19];
  const float* fc2w = (const float*)d_in[20];
  const float* fc2b = (const float*)d_in[21];
  float* out = (float*)d_out;

  // workspace layout:
  //   [0, 13.1MB)       : wT exp-logits bf16 [1600][B]
  //   [13.1MB, +4.10MB) : Bf (100*20480 shorts)
  //   then W1f 32,768 B, W2f 4,096 B
  const size_t W_BYTES = (size_t)NB * NRODT * 2;     // 13,107,200
  unsigned short* wTbuf = (unsigned short*)d_ws;
  unsigned short* Bfb   = (unsigned short*)((char*)d_ws + W_BYTES);
  unsigned short* W1fb  = (unsigned short*)((char*)d_ws + W_BYTES + 4096000);
  unsigned short* W2fb  = (unsigned short*)((char*)d_ws + W_BYTES + 4096000 + 32768);

  k01_prep<<<1600 + NFOR + 2 + 3, 256, 0, stream>>>(
      x, w1, b1, perm, gn1w, gn1b, c2w, c2b, gn2w, gn2b, c3w, c3b,
      E, swr, fc1w, fc2w, wTbuf, Bfb, W1fb, W2fb, out);
  dim3 g3(NB / 128, NFOR);
  k3_mfma<<<g3, 256, 0, stream>>>(wTbuf, swr, Bfb, W1fb, W2fb,
                                  ln1w, ln1b, fc1b, ln2w, ln2b, fc2b, out);
}